// Round 10
// baseline (374.248 us; speedup 1.0000x reference)
//
#include <hip/hip_runtime.h>

#define KNN_K 8
constexpr int B = 32;
constexpr int N = 2048;
constexpr int M = B * N;  // 65536 points

typedef __attribute__((ext_vector_type(8))) short short8v;  // 8 bf16
typedef __attribute__((ext_vector_type(4))) float f32x4;

__device__ __forceinline__ float lrelu_max(float m, float y) {
  return fmaxf(m, fmaxf(y, 0.2f * y));
}
__device__ __forceinline__ unsigned short f2bf(float x) {  // RNE f32->bf16
  unsigned int u = __float_as_uint(x);
  unsigned int r = u + 0x7FFFu + ((u >> 16) & 1u);
  return (unsigned short)(r >> 16);
}
__device__ __forceinline__ float bf2f(unsigned short h) {
  return __uint_as_float(((unsigned int)h) << 16);
}

// ---------------- KNN on reshape(xyz,(B,3,N)) pseudo-points ----------------
// 8 threads/query, interleaved eighths (m = 8j+q). Deferred selection in
// registers: hot scan = pd + cmp + shift-in push to an 8-deep register
// queue; wave-voted flush sorts the queue (19-CAS odd-even, exact u64 keys)
// and bitonic-merges into the sorted per-thread top-8. 8-way head-merge at
// the end. No LDS beyond the 32KB point cache (merge scratch aliases it).
__device__ __forceinline__ unsigned int mono_f32(float f) {
  unsigned int u = __float_as_uint(f);
  return (u & 0x80000000u) ? ~u : (u | 0x80000000u);
}

#define CAS_T(i, j)                                        \
  {                                                        \
    unsigned long long _x = t[i], _y = t[j];               \
    bool _p = _x < _y;                                     \
    t[i] = _p ? _y : _x;                                   \
    t[j] = _p ? _x : _y;                                   \
  }
#define CAS_TOP(i, j)                                      \
  {                                                        \
    unsigned long long _x = top[i], _y = top[j];           \
    bool _p = _x < _y;                                     \
    top[i] = _p ? _y : _x;                                 \
    top[j] = _p ? _x : _y;                                 \
  }

__global__ __launch_bounds__(256) void knn_kernel(const float* __restrict__ xyz,
                                                  int* __restrict__ idx) {
  __shared__ __align__(16) float4 spt[N];  // 32 KB; reused as merge scratch
  int b = blockIdx.x >> 6;     // 64 blocks per batch
  int nblk = blockIdx.x & 63;  // 32 queries per block
  const float* F = xyz + (size_t)b * N * 3;
  for (int i = threadIdx.x; i < N; i += 256) {
    float x = F[i], y = F[N + i], z = F[2 * N + i];
    spt[i] = make_float4(x, y, z, (x * x + y * y) + z * z);
  }
  __syncthreads();
  const int tid = (int)threadIdx.x;
  const int ln = tid >> 3;  // 0..31 local query
  const int q = tid & 7;    // eighth
  const int n = nblk * 32 + ln;
  float4 pn = spt[n];

  unsigned long long top[8];   // sorted desc u64 keys; 0 = empty
  unsigned long long bufr[8];  // shift-in queue; entries >= cnt are stale
#pragma unroll
  for (int k = 0; k < 8; ++k) { top[k] = 0ull; bufr[k] = 0ull; }
  float thr = -1e30f;
  int cnt = 0;

  auto flush = [&]() {
    unsigned long long t[8];
#pragma unroll
    for (int i = 0; i < 8; ++i) t[i] = (i < cnt) ? bufr[i] : 0ull;
    // odd-even mergesort 8, descending (19 CAS)
    CAS_T(0, 1) CAS_T(2, 3) CAS_T(4, 5) CAS_T(6, 7)
    CAS_T(0, 2) CAS_T(1, 3) CAS_T(4, 6) CAS_T(5, 7)
    CAS_T(1, 2) CAS_T(5, 6)
    CAS_T(0, 4) CAS_T(1, 5) CAS_T(2, 6) CAS_T(3, 7)
    CAS_T(2, 4) CAS_T(3, 5)
    CAS_T(1, 2) CAS_T(3, 4) CAS_T(5, 6)
    // bitonic half-clean: keep top-8 of (top ++ reverse(t))
#pragma unroll
    for (int i = 0; i < 8; ++i) {
      unsigned long long x = top[i], y = t[7 - i];
      top[i] = x > y ? x : y;
    }
    // bitonic clean 8 desc (12 CAS)
    CAS_TOP(0, 4) CAS_TOP(1, 5) CAS_TOP(2, 6) CAS_TOP(3, 7)
    CAS_TOP(0, 2) CAS_TOP(1, 3) CAS_TOP(4, 6) CAS_TOP(5, 7)
    CAS_TOP(0, 1) CAS_TOP(2, 3) CAS_TOP(4, 5) CAS_TOP(6, 7)
    cnt = 0;
    unsigned int u = (unsigned int)(top[7] >> 32);
    thr = __uint_as_float((u & 0x80000000u) ? (u & 0x7FFFFFFFu) : ~u);
  };

#pragma unroll 4
  for (int j = 0; j < N / 8; ++j) {
    int m = (j << 3) | q;
    float4 pm = spt[m];
    float dot = (pn.x * pm.x + pn.y * pm.y) + pn.z * pm.z;
    float inner = -2.0f * dot;
    float pd = -pn.w - inner - pm.w;  // reference arithmetic order
    if (pd > thr) {  // strict: ties keep the earlier (lower) index, as top_k
      unsigned long long key =
          ((unsigned long long)mono_f32(pd) << 32) |
          (unsigned long long)(0xFFFFFFFFu - (unsigned int)m);
      bufr[7] = bufr[6]; bufr[6] = bufr[5]; bufr[5] = bufr[4];
      bufr[4] = bufr[3]; bufr[3] = bufr[2]; bufr[2] = bufr[1];
      bufr[1] = bufr[0]; bufr[0] = key;
      ++cnt;
    }
    if (__any(cnt >= 8)) flush();
  }
  flush();  // drain partial queues

  __syncthreads();  // all scans done; safe to overwrite spt
  unsigned long long* km = (unsigned long long*)spt;  // [256][8] = 16 KB
#pragma unroll
  for (int k = 0; k < 8; ++k) km[tid * 8 + k] = top[k];
  __syncthreads();
  if (q == 0) {
    int h[8] = {0, 0, 0, 0, 0, 0, 0, 0};
    int* op = idx + ((size_t)b * N + n) * KNN_K;
#pragma unroll
    for (int k = 0; k < KNN_K; ++k) {
      unsigned long long bk = 0ull;
      int bq = 0;
#pragma unroll
      for (int qq = 0; qq < 8; ++qq) {
        unsigned long long kk = km[(((ln << 3) | qq)) * 8 + h[qq]];
        if (kk > bk) { bk = kk; bq = qq; }
      }
      op[k] = (int)(0xFFFFFFFFu - (unsigned int)(bk & 0xFFFFFFFFull));
      h[bq]++;
    }
  }
}

// ---------------- layer-1 transform (tiny K): f32 VALU path ----------------
template <int CI, int CO>
__global__ __launch_bounds__(256) void transform_kernel(
    const float* __restrict__ f, const float* __restrict__ W,
    const float* __restrict__ s, const float* __restrict__ bsh,
    float* __restrict__ G, float* __restrict__ C) {
  constexpr int KC = CI;  // CI == 4 only
  __shared__ __align__(16) float fs[KC][68];
  __shared__ __align__(16) float was[KC][68];
  __shared__ __align__(16) float wds[KC][68];
  const int base = blockIdx.x * 64;
  const int o0 = blockIdx.y * 64;
  const int tid = threadIdx.x;
  const int tx = tid & 15, ty = tid >> 4;
  float accG[4][4] = {{0}};
  float accC[4][4] = {{0}};
  for (int i = tid; i < 64 * 4; i += 256) {
    int c = i & 3, p = i >> 2;
    fs[c][p] = (c < 3) ? f[(size_t)(base + p) * 3 + c] : 0.0f;
  }
  if (tid < 64) {
    int o = tid;
    float sc = s[o0 + o];
    const float* wr = &W[(size_t)(o0 + o) * 6];
#pragma unroll
    for (int c = 0; c < 4; ++c) {
      float wa = (c < 3) ? wr[c] : 0.0f;
      float wb = (c < 3) ? wr[3 + c] : 0.0f;
      was[c][o] = sc * wa;
      wds[c][o] = sc * (wb - wa);
    }
  }
  __syncthreads();
#pragma unroll
  for (int c = 0; c < KC; ++c) {
    float4 av = *(const float4*)&fs[c][ty * 4];
    float4 wg = *(const float4*)&was[c][tx * 4];
    float4 wd = *(const float4*)&wds[c][tx * 4];
    float a[4] = {av.x, av.y, av.z, av.w};
    float g[4] = {wg.x, wg.y, wg.z, wg.w};
    float d[4] = {wd.x, wd.y, wd.z, wd.w};
#pragma unroll
    for (int i = 0; i < 4; ++i)
#pragma unroll
      for (int j = 0; j < 4; ++j) {
        accG[i][j] = fmaf(a[i], g[j], accG[i][j]);
        accC[i][j] = fmaf(a[i], d[j], accC[i][j]);
      }
  }
  float4 sh = *(const float4*)&bsh[o0 + tx * 4];
  float shv[4] = {sh.x, sh.y, sh.z, sh.w};
#pragma unroll
  for (int i = 0; i < 4; ++i) {
    size_t row = (size_t)(base + ty * 4 + i);
    float4 g4 = make_float4(accG[i][0], accG[i][1], accG[i][2], accG[i][3]);
    float4 c4 = make_float4(accC[i][0] + shv[0], accC[i][1] + shv[1],
                            accC[i][2] + shv[2], accC[i][3] + shv[3]);
    *(float4*)&G[row * CO + o0 + tx * 4] = g4;
    *(float4*)&C[row * CO + o0 + tx * 4] = c4;
  }
}

// ------------- weight prep: split s*Wa, s*(Wb-Wa) into bf16 hi/lo ----------
template <int CI, int CO>
__global__ __launch_bounds__(256) void wprep_kernel(
    const float* __restrict__ W, const float* __restrict__ s,
    unsigned short* __restrict__ wb) {
  int i = blockIdx.x * 256 + (int)threadIdx.x;  // o*CI + k
  if (i >= CI * CO) return;
  int o = i / CI, k = i % CI;
  float sc = s[o];
  float w0 = W[(size_t)o * 2 * CI + k];
  float wa = sc * w0;
  float wd = sc * (W[(size_t)o * 2 * CI + CI + k] - w0);
  unsigned short waH = f2bf(wa);
  unsigned short waL = f2bf(wa - bf2f(waH));
  unsigned short wdH = f2bf(wd);
  unsigned short wdL = f2bf(wd - bf2f(wdH));
  wb[i] = waH;
  wb[CI * CO + i] = waL;
  wb[2 * CI * CO + i] = wdH;
  wb[3 * CI * CO + i] = wdL;
}

// --------- MFMA transform: G/C = A(hi+lo) @ W(hi+lo), 3-pass bf16 ---------
// tile 128 pts x 64 outs, 4 waves (2x2), wave tile 64x32; K-chunks of 32.
template <int K, int CO>
__global__ __launch_bounds__(256) void mfma_transform_kernel(
    const unsigned short* __restrict__ AHi, const unsigned short* __restrict__ ALo,
    const unsigned short* __restrict__ wb, const float* __restrict__ bsh,
    float* __restrict__ G, float* __restrict__ C, size_t arrStride) {
  constexpr int KP = 40;  // padded LDS k-stride (bf16) -> 80B rows, no 8-way conflict
  __shared__ unsigned short Ah[128][KP];
  __shared__ unsigned short Al[128][KP];
  __shared__ unsigned short Bw[4][64][KP];
  const int base = blockIdx.x * 128;
  const int o0 = blockIdx.y * 64;
  const int tid = (int)threadIdx.x;
  const int lane = tid & 63;
  const int wid = tid >> 6;
  const int wr = wid >> 1;  // wave row-half (64 pts)
  const int wc = wid & 1;   // wave col-half (32 outs)
  const int l15 = lane & 15;
  const int lk = (lane >> 4) * 8;  // fragment k-base

  f32x4 zero = {0.f, 0.f, 0.f, 0.f};
  f32x4 accG[4][2], accC[4][2];
#pragma unroll
  for (int i = 0; i < 4; ++i)
#pragma unroll
    for (int j = 0; j < 2; ++j) { accG[i][j] = zero; accC[i][j] = zero; }

  const int arow = tid >> 1;        // 0..127
  const int akh = (tid & 1) * 16;   // 0 / 16
  const int bo = tid & 63;          // weight out-row
  const int barr = tid >> 6;        // which of 4 arrays

  for (int kc0 = 0; kc0 < K; kc0 += 32) {
    {  // stage A hi/lo: 128 x 32 bf16 each
      const unsigned short* pa = &AHi[(size_t)(base + arow) * K + kc0 + akh];
      short8v h0 = *(const short8v*)pa;
      short8v h1 = *(const short8v*)(pa + 8);
      *(short8v*)&Ah[arow][akh] = h0;
      *(short8v*)&Ah[arow][akh + 8] = h1;
      const unsigned short* pl = &ALo[(size_t)(base + arow) * K + kc0 + akh];
      short8v l0 = *(const short8v*)pl;
      short8v l1 = *(const short8v*)(pl + 8);
      *(short8v*)&Al[arow][akh] = l0;
      *(short8v*)&Al[arow][akh + 8] = l1;
      // stage B: 4 arrays x 64 outs x 32 k
      const unsigned short* pb =
          &wb[(size_t)barr * arrStride + (size_t)(o0 + bo) * K + kc0];
#pragma unroll
      for (int j = 0; j < 4; ++j) {
        short8v v = *(const short8v*)(pb + j * 8);
        *(short8v*)&Bw[barr][bo][j * 8] = v;
      }
    }
    __syncthreads();
    short8v ah[4], al[4], bah[2], bal[2], bdh[2], bdl[2];
#pragma unroll
    for (int mf = 0; mf < 4; ++mf) {
      ah[mf] = *(const short8v*)&Ah[wr * 64 + mf * 16 + l15][lk];
      al[mf] = *(const short8v*)&Al[wr * 64 + mf * 16 + l15][lk];
    }
#pragma unroll
    for (int nf = 0; nf < 2; ++nf) {
      int oo = wc * 32 + nf * 16 + l15;
      bah[nf] = *(const short8v*)&Bw[0][oo][lk];
      bal[nf] = *(const short8v*)&Bw[1][oo][lk];
      bdh[nf] = *(const short8v*)&Bw[2][oo][lk];
      bdl[nf] = *(const short8v*)&Bw[3][oo][lk];
    }
#pragma unroll
    for (int mf = 0; mf < 4; ++mf)
#pragma unroll
      for (int nf = 0; nf < 2; ++nf) {
        accG[mf][nf] = __builtin_amdgcn_mfma_f32_16x16x32_bf16(
            ah[mf], bah[nf], accG[mf][nf], 0, 0, 0);
        accG[mf][nf] = __builtin_amdgcn_mfma_f32_16x16x32_bf16(
            ah[mf], bal[nf], accG[mf][nf], 0, 0, 0);
        accG[mf][nf] = __builtin_amdgcn_mfma_f32_16x16x32_bf16(
            al[mf], bah[nf], accG[mf][nf], 0, 0, 0);
        accC[mf][nf] = __builtin_amdgcn_mfma_f32_16x16x32_bf16(
            ah[mf], bdh[nf], accC[mf][nf], 0, 0, 0);
        accC[mf][nf] = __builtin_amdgcn_mfma_f32_16x16x32_bf16(
            ah[mf], bdl[nf], accC[mf][nf], 0, 0, 0);
        accC[mf][nf] = __builtin_amdgcn_mfma_f32_16x16x32_bf16(
            al[mf], bdh[nf], accC[mf][nf], 0, 0, 0);
      }
    __syncthreads();
  }
  float sh[2];
  sh[0] = bsh[o0 + wc * 32 + l15];
  sh[1] = bsh[o0 + wc * 32 + 16 + l15];
#pragma unroll
  for (int mf = 0; mf < 4; ++mf)
#pragma unroll
    for (int nf = 0; nf < 2; ++nf) {
      int col = o0 + wc * 32 + nf * 16 + l15;
#pragma unroll
      for (int r = 0; r < 4; ++r) {
        int row = base + wr * 64 + mf * 16 + (lane >> 4) * 4 + r;
        G[(size_t)row * CO + col] = accG[mf][nf][r];
        C[(size_t)row * CO + col] = accC[mf][nf][r] + sh[nf];
      }
    }
}

// ------- gather + leaky + max over k; emits bf16 hi/lo feature split -------
template <int CO>
__global__ __launch_bounds__(256) void gatherbf_kernel(
    const float* __restrict__ G, const float* __restrict__ C,
    const int* __restrict__ idx, unsigned short* __restrict__ outHi,
    unsigned short* __restrict__ outLo) {
  constexpr int O4 = CO / 4;
  int gid = blockIdx.x * 256 + (int)threadIdx.x;
  int o4 = gid % O4;
  int bn = gid / O4;
  int b = bn >> 11;
  const int* ip = &idx[(size_t)bn * KNN_K];
  const float* Gb = G + (size_t)b * N * CO;
  float4 cv = *(const float4*)&C[(size_t)bn * CO + o4 * 4];
  float4 m = make_float4(-1e30f, -1e30f, -1e30f, -1e30f);
#pragma unroll
  for (int k = 0; k < KNN_K; ++k) {
    int nb = ip[k];
    float4 g = *(const float4*)&Gb[(size_t)nb * CO + o4 * 4];
    m.x = lrelu_max(m.x, g.x + cv.x);
    m.y = lrelu_max(m.y, g.y + cv.y);
    m.z = lrelu_max(m.z, g.z + cv.z);
    m.w = lrelu_max(m.w, g.w + cv.w);
  }
  ushort4 hi, lo;
  hi.x = f2bf(m.x); lo.x = f2bf(m.x - bf2f(hi.x));
  hi.y = f2bf(m.y); lo.y = f2bf(m.y - bf2f(hi.y));
  hi.z = f2bf(m.z); lo.z = f2bf(m.z - bf2f(hi.z));
  hi.w = f2bf(m.w); lo.w = f2bf(m.w - bf2f(hi.w));
  *(ushort4*)&outHi[(size_t)bn * CO + o4 * 4] = hi;
  *(ushort4*)&outLo[(size_t)bn * CO + o4 * 4] = lo;
}

// ---------------- last layer: gather + max over k, partial max over n ------
template <int CO>
__global__ __launch_bounds__(256) void gather_last_kernel(
    const float* __restrict__ G, const float* __restrict__ C,
    const int* __restrict__ idx, float* __restrict__ part) {
  constexpr int O4 = CO / 4;
  constexpr int PL = 256 / O4;
  constexpr int ITER = 128 / PL;
  int b = blockIdx.x >> 4;
  int chunk = blockIdx.x & 15;
  int tid = (int)threadIdx.x;
  int o4 = tid % O4;
  int pl = tid / O4;
  const float* Gb = G + (size_t)b * N * CO;
  float4 m = make_float4(-1e30f, -1e30f, -1e30f, -1e30f);
  for (int it = 0; it < ITER; ++it) {
    int n = chunk * 128 + it * PL + pl;
    size_t bn = (size_t)b * N + n;
    const int* ip = &idx[bn * KNN_K];
    float4 cv = *(const float4*)&C[bn * CO + o4 * 4];
#pragma unroll
    for (int k = 0; k < KNN_K; ++k) {
      int nb = ip[k];
      float4 g = *(const float4*)&Gb[(size_t)nb * CO + o4 * 4];
      m.x = lrelu_max(m.x, g.x + cv.x);
      m.y = lrelu_max(m.y, g.y + cv.y);
      m.z = lrelu_max(m.z, g.z + cv.z);
      m.w = lrelu_max(m.w, g.w + cv.w);
    }
  }
  __shared__ __align__(16) float4 red[256];
  red[tid] = m;
  __syncthreads();
  for (int s = 128; s >= O4; s >>= 1) {
    if (tid < s) {
      float4 a = red[tid], bb = red[tid + s];
      red[tid] = make_float4(fmaxf(a.x, bb.x), fmaxf(a.y, bb.y),
                             fmaxf(a.z, bb.z), fmaxf(a.w, bb.w));
    }
    __syncthreads();
  }
  if (tid < O4) {
    *(float4*)&part[((size_t)(b * 16 + chunk)) * CO + tid * 4] = red[tid];
  }
}

template <int CO>
__global__ __launch_bounds__(256) void reduce_kernel(const float* __restrict__ part,
                                                     float* __restrict__ out,
                                                     int ooff) {
  constexpr int O4 = CO / 4;
  int gid = blockIdx.x * 256 + (int)threadIdx.x;
  int b = gid / O4;
  int o4 = gid % O4;
  float4 m = make_float4(-1e30f, -1e30f, -1e30f, -1e30f);
  for (int ch = 0; ch < 16; ++ch) {
    float4 v = *(const float4*)&part[((size_t)(b * 16 + ch)) * CO + o4 * 4];
    m.x = fmaxf(m.x, v.x); m.y = fmaxf(m.y, v.y);
    m.z = fmaxf(m.z, v.z); m.w = fmaxf(m.w, v.w);
  }
  *(float4*)&out[(size_t)b * 256 + ooff + o4 * 4] = m;
}

extern "C" void kernel_launch(void* const* d_in, const int* in_sizes, int n_in,
                              void* d_out, int out_size, void* d_ws, size_t ws_size,
                              hipStream_t stream) {
  const float* xyz = (const float*)d_in[0];
  const float* W0 = (const float*)d_in[1];
  const float* s0 = (const float*)d_in[2];
  const float* b0 = (const float*)d_in[3];
  const float* W1 = (const float*)d_in[4];
  const float* s1 = (const float*)d_in[5];
  const float* b1 = (const float*)d_in[6];
  const float* W2 = (const float*)d_in[7];
  const float* s2 = (const float*)d_in[8];
  const float* b2 = (const float*)d_in[9];
  float* out = (float*)d_out;

  const size_t MB = 1024 * 1024;
  char* ws = (char*)d_ws;
  int* idx = (int*)ws;                                        // 2 MB
  unsigned short* FHi = (unsigned short*)(ws + 2 * MB);       // 16 MB (M x <=128 bf16)
  unsigned short* FLo = (unsigned short*)(ws + 18 * MB);      // 16 MB
  float* G = (float*)(ws + 34 * MB);                          // 32 MB
  float* Cb = (float*)(ws + 66 * MB);                         // 32 MB
  unsigned short* wbuf = (unsigned short*)(ws + 98 * MB);     // 256 KB
  float* part = (float*)(ws + 98 * MB + 256 * 1024);          // 256 KB

  knn_kernel<<<B * 64, 256, 0, stream>>>(xyz, idx);

  // Layer 1: ci=3 (pad 4), co=64 — f32 path, output split to bf16 hi/lo
  transform_kernel<4, 64><<<dim3(M / 64, 1), 256, 0, stream>>>(xyz, W0, s0, b0, G, Cb);
  gatherbf_kernel<64><<<M * 16 / 256, 256, 0, stream>>>(G, Cb, idx, FHi, FLo);

  // Layer 2: K=64, CO=128 — MFMA 3-pass bf16 split
  wprep_kernel<64, 128><<<(64 * 128 + 255) / 256, 256, 0, stream>>>(W1, s1, wbuf);
  mfma_transform_kernel<64, 128><<<dim3(M / 128, 2), 256, 0, stream>>>(
      FHi, FLo, wbuf, b1, G, Cb, (size_t)64 * 128);
  gatherbf_kernel<128><<<M * 32 / 256, 256, 0, stream>>>(G, Cb, idx, FHi, FLo);

  // Layer 3: K=128, CO=256 in two 128-channel halves — MFMA
  wprep_kernel<128, 256><<<(128 * 256 + 255) / 256, 256, 0, stream>>>(W2, s2, wbuf);
  for (int h = 0; h < 2; ++h) {
    mfma_transform_kernel<128, 128><<<dim3(M / 128, 2), 256, 0, stream>>>(
        FHi, FLo, wbuf + (size_t)h * 128 * 128, b2 + h * 128, G, Cb,
        (size_t)128 * 256);
    gather_last_kernel<128><<<B * 16, 256, 0, stream>>>(G, Cb, idx, part);
    reduce_kernel<128><<<B * 128 / 4 / 256, 256, 0, stream>>>(part, out, h * 128);
  }
}

// Round 11
// 350.879 us; speedup vs baseline: 1.0666x; 1.0666x over previous
//
#include <hip/hip_runtime.h>

#define KNN_K 8
constexpr int B = 32;
constexpr int N = 2048;
constexpr int M = B * N;  // 65536 points

typedef __attribute__((ext_vector_type(8))) short short8v;  // 8 bf16
typedef __attribute__((ext_vector_type(4))) float f32x4;

__device__ __forceinline__ float lrelu_max(float m, float y) {
  return fmaxf(m, fmaxf(y, 0.2f * y));
}
__device__ __forceinline__ unsigned short f2bf(float x) {  // RNE f32->bf16
  unsigned int u = __float_as_uint(x);
  unsigned int r = u + 0x7FFFu + ((u >> 16) & 1u);
  return (unsigned short)(r >> 16);
}
__device__ __forceinline__ float bf2f(unsigned short h) {
  return __uint_as_float(((unsigned int)h) << 16);
}

// ---------------- KNN on reshape(xyz,(B,3,N)) pseudo-points ----------------
// 4 threads/query, interleaved quarters (round-9 geometry). Deferred
// selection in registers with a 4-deep shift-in queue (cheap accept body);
// wave-voted flush: 5-CAS sort-4 + 4-max/12-CAS bitonic merge into sorted
// top-8 (exact u64 keys). thr update guarded against the not-yet-full case.
__device__ __forceinline__ unsigned int mono_f32(float f) {
  unsigned int u = __float_as_uint(f);
  return (u & 0x80000000u) ? ~u : (u | 0x80000000u);
}

#define CAS_T(i, j)                                        \
  {                                                        \
    unsigned long long _x = t[i], _y = t[j];               \
    bool _p = _x < _y;                                     \
    t[i] = _p ? _y : _x;                                   \
    t[j] = _p ? _x : _y;                                   \
  }
#define CAS_TOP(i, j)                                      \
  {                                                        \
    unsigned long long _x = top[i], _y = top[j];           \
    bool _p = _x < _y;                                     \
    top[i] = _p ? _y : _x;                                 \
    top[j] = _p ? _x : _y;                                 \
  }

__global__ __launch_bounds__(256) void knn_kernel(const float* __restrict__ xyz,
                                                  int* __restrict__ idx) {
  __shared__ __align__(16) float4 spt[N];  // 32 KB; reused as merge scratch
  int b = blockIdx.x >> 5;     // 32 blocks per batch
  int nblk = blockIdx.x & 31;  // 64 queries per block
  const float* F = xyz + (size_t)b * N * 3;
  for (int i = threadIdx.x; i < N; i += 256) {
    float x = F[i], y = F[N + i], z = F[2 * N + i];
    spt[i] = make_float4(x, y, z, (x * x + y * y) + z * z);
  }
  __syncthreads();
  const int tid = (int)threadIdx.x;
  const int ln = tid >> 2;  // 0..63 local query
  const int q = tid & 3;    // quarter
  const int n = nblk * 64 + ln;
  float4 pn = spt[n];
  const float npnw = -pn.w;

  unsigned long long top[8];   // sorted desc u64 keys; 0 = empty
  unsigned long long bufr[4];  // 4-deep shift-in queue; entries >= cnt stale
#pragma unroll
  for (int k = 0; k < 8; ++k) top[k] = 0ull;
#pragma unroll
  for (int k = 0; k < 4; ++k) bufr[k] = 0ull;
  float thr = -1e30f;
  int cnt = 0;

  auto flush = [&]() {
    unsigned long long t[4];
#pragma unroll
    for (int i = 0; i < 4; ++i) t[i] = (i < cnt) ? bufr[i] : 0ull;
    // sort 4 desc (5 CAS)
    CAS_T(0, 1) CAS_T(2, 3) CAS_T(0, 2) CAS_T(1, 3) CAS_T(1, 2)
    // bitonic half-clean vs zero-padded reversed t: only tail touched
    {
      unsigned long long x;
      x = top[4]; top[4] = x > t[3] ? x : t[3];
      x = top[5]; top[5] = x > t[2] ? x : t[2];
      x = top[6]; top[6] = x > t[1] ? x : t[1];
      x = top[7]; top[7] = x > t[0] ? x : t[0];
    }
    // bitonic clean 8 desc (12 CAS)
    CAS_TOP(0, 4) CAS_TOP(1, 5) CAS_TOP(2, 6) CAS_TOP(3, 7)
    CAS_TOP(0, 2) CAS_TOP(1, 3) CAS_TOP(4, 6) CAS_TOP(5, 7)
    CAS_TOP(0, 1) CAS_TOP(2, 3) CAS_TOP(4, 5) CAS_TOP(6, 7)
    cnt = 0;
    if (top[7] != 0ull) {  // guard: while not full, keep thr=-1e30 (accept all)
      unsigned int u = (unsigned int)(top[7] >> 32);
      thr = __uint_as_float((u & 0x80000000u) ? (u & 0x7FFFFFFFu) : ~u);
    }
  };

#pragma unroll 4
  for (int j = 0; j < N / 4; ++j) {
    int m = (j << 2) | q;
    float4 pm = spt[m];
    float dot = (pn.x * pm.x + pn.y * pm.y) + pn.z * pm.z;
    float inner = -2.0f * dot;
    float pd = npnw - inner - pm.w;  // reference arithmetic order
    if (pd > thr) {  // strict: ties keep the earlier (lower) index, as top_k
      unsigned long long key =
          ((unsigned long long)mono_f32(pd) << 32) |
          (unsigned long long)(0xFFFFFFFFu - (unsigned int)m);
      bufr[3] = bufr[2]; bufr[2] = bufr[1]; bufr[1] = bufr[0];
      bufr[0] = key;
      ++cnt;
    }
    if (__any(cnt >= 4)) flush();
  }
  flush();  // drain partial queues

  __syncthreads();  // all scans done; safe to overwrite spt
  unsigned long long* km = (unsigned long long*)spt;  // [256][8] = 16 KB
#pragma unroll
  for (int k = 0; k < 8; ++k) km[tid * 8 + k] = top[k];
  __syncthreads();
  if (q == 0) {
    int h[4] = {0, 0, 0, 0};
    int* op = idx + ((size_t)b * N + n) * KNN_K;
#pragma unroll
    for (int k = 0; k < KNN_K; ++k) {
      unsigned long long bk = 0ull;
      int bq = 0;
#pragma unroll
      for (int qq = 0; qq < 4; ++qq) {
        unsigned long long kk = km[(((ln << 2) | qq)) * 8 + h[qq]];
        if (kk > bk) { bk = kk; bq = qq; }
      }
      op[k] = (int)(0xFFFFFFFFu - (unsigned int)(bk & 0xFFFFFFFFull));
      h[bq]++;
    }
  }
}

// ---------------- layer-1 transform (tiny K): f32 VALU path ----------------
template <int CI, int CO>
__global__ __launch_bounds__(256) void transform_kernel(
    const float* __restrict__ f, const float* __restrict__ W,
    const float* __restrict__ s, const float* __restrict__ bsh,
    float* __restrict__ G, float* __restrict__ C) {
  constexpr int KC = CI;  // CI == 4 only
  __shared__ __align__(16) float fs[KC][68];
  __shared__ __align__(16) float was[KC][68];
  __shared__ __align__(16) float wds[KC][68];
  const int base = blockIdx.x * 64;
  const int o0 = blockIdx.y * 64;
  const int tid = threadIdx.x;
  const int tx = tid & 15, ty = tid >> 4;
  float accG[4][4] = {{0}};
  float accC[4][4] = {{0}};
  for (int i = tid; i < 64 * 4; i += 256) {
    int c = i & 3, p = i >> 2;
    fs[c][p] = (c < 3) ? f[(size_t)(base + p) * 3 + c] : 0.0f;
  }
  if (tid < 64) {
    int o = tid;
    float sc = s[o0 + o];
    const float* wr = &W[(size_t)(o0 + o) * 6];
#pragma unroll
    for (int c = 0; c < 4; ++c) {
      float wa = (c < 3) ? wr[c] : 0.0f;
      float wb = (c < 3) ? wr[3 + c] : 0.0f;
      was[c][o] = sc * wa;
      wds[c][o] = sc * (wb - wa);
    }
  }
  __syncthreads();
#pragma unroll
  for (int c = 0; c < KC; ++c) {
    float4 av = *(const float4*)&fs[c][ty * 4];
    float4 wg = *(const float4*)&was[c][tx * 4];
    float4 wd = *(const float4*)&wds[c][tx * 4];
    float a[4] = {av.x, av.y, av.z, av.w};
    float g[4] = {wg.x, wg.y, wg.z, wg.w};
    float d[4] = {wd.x, wd.y, wd.z, wd.w};
#pragma unroll
    for (int i = 0; i < 4; ++i)
#pragma unroll
      for (int j = 0; j < 4; ++j) {
        accG[i][j] = fmaf(a[i], g[j], accG[i][j]);
        accC[i][j] = fmaf(a[i], d[j], accC[i][j]);
      }
  }
  float4 sh = *(const float4*)&bsh[o0 + tx * 4];
  float shv[4] = {sh.x, sh.y, sh.z, sh.w};
#pragma unroll
  for (int i = 0; i < 4; ++i) {
    size_t row = (size_t)(base + ty * 4 + i);
    float4 g4 = make_float4(accG[i][0], accG[i][1], accG[i][2], accG[i][3]);
    float4 c4 = make_float4(accC[i][0] + shv[0], accC[i][1] + shv[1],
                            accC[i][2] + shv[2], accC[i][3] + shv[3]);
    *(float4*)&G[row * CO + o0 + tx * 4] = g4;
    *(float4*)&C[row * CO + o0 + tx * 4] = c4;
  }
}

// ------------- weight prep: split s*Wa, s*(Wb-Wa) into bf16 hi/lo ----------
template <int CI, int CO>
__global__ __launch_bounds__(256) void wprep_kernel(
    const float* __restrict__ W, const float* __restrict__ s,
    unsigned short* __restrict__ wb) {
  int i = blockIdx.x * 256 + (int)threadIdx.x;  // o*CI + k
  if (i >= CI * CO) return;
  int o = i / CI, k = i % CI;
  float sc = s[o];
  float w0 = W[(size_t)o * 2 * CI + k];
  float wa = sc * w0;
  float wd = sc * (W[(size_t)o * 2 * CI + CI + k] - w0);
  unsigned short waH = f2bf(wa);
  unsigned short waL = f2bf(wa - bf2f(waH));
  unsigned short wdH = f2bf(wd);
  unsigned short wdL = f2bf(wd - bf2f(wdH));
  wb[i] = waH;
  wb[CI * CO + i] = waL;
  wb[2 * CI * CO + i] = wdH;
  wb[3 * CI * CO + i] = wdL;
}

// --------- MFMA transform: G/C = A(hi+lo) @ W(hi+lo), 3-pass bf16 ---------
// tile 128 pts x 64 outs, 4 waves (2x2), wave tile 64x32; K-chunks of 32.
template <int K, int CO>
__global__ __launch_bounds__(256) void mfma_transform_kernel(
    const unsigned short* __restrict__ AHi, const unsigned short* __restrict__ ALo,
    const unsigned short* __restrict__ wb, const float* __restrict__ bsh,
    float* __restrict__ G, float* __restrict__ C, size_t arrStride) {
  constexpr int KP = 40;  // padded LDS k-stride (bf16) -> 80B rows, no 8-way conflict
  __shared__ unsigned short Ah[128][KP];
  __shared__ unsigned short Al[128][KP];
  __shared__ unsigned short Bw[4][64][KP];
  const int base = blockIdx.x * 128;
  const int o0 = blockIdx.y * 64;
  const int tid = (int)threadIdx.x;
  const int lane = tid & 63;
  const int wid = tid >> 6;
  const int wr = wid >> 1;  // wave row-half (64 pts)
  const int wc = wid & 1;   // wave col-half (32 outs)
  const int l15 = lane & 15;
  const int lk = (lane >> 4) * 8;  // fragment k-base

  f32x4 zero = {0.f, 0.f, 0.f, 0.f};
  f32x4 accG[4][2], accC[4][2];
#pragma unroll
  for (int i = 0; i < 4; ++i)
#pragma unroll
    for (int j = 0; j < 2; ++j) { accG[i][j] = zero; accC[i][j] = zero; }

  const int arow = tid >> 1;        // 0..127
  const int akh = (tid & 1) * 16;   // 0 / 16
  const int bo = tid & 63;          // weight out-row
  const int barr = tid >> 6;        // which of 4 arrays

  for (int kc0 = 0; kc0 < K; kc0 += 32) {
    {  // stage A hi/lo: 128 x 32 bf16 each
      const unsigned short* pa = &AHi[(size_t)(base + arow) * K + kc0 + akh];
      short8v h0 = *(const short8v*)pa;
      short8v h1 = *(const short8v*)(pa + 8);
      *(short8v*)&Ah[arow][akh] = h0;
      *(short8v*)&Ah[arow][akh + 8] = h1;
      const unsigned short* pl = &ALo[(size_t)(base + arow) * K + kc0 + akh];
      short8v l0 = *(const short8v*)pl;
      short8v l1 = *(const short8v*)(pl + 8);
      *(short8v*)&Al[arow][akh] = l0;
      *(short8v*)&Al[arow][akh + 8] = l1;
      // stage B: 4 arrays x 64 outs x 32 k
      const unsigned short* pb =
          &wb[(size_t)barr * arrStride + (size_t)(o0 + bo) * K + kc0];
#pragma unroll
      for (int j = 0; j < 4; ++j) {
        short8v v = *(const short8v*)(pb + j * 8);
        *(short8v*)&Bw[barr][bo][j * 8] = v;
      }
    }
    __syncthreads();
    short8v ah[4], al[4], bah[2], bal[2], bdh[2], bdl[2];
#pragma unroll
    for (int mf = 0; mf < 4; ++mf) {
      ah[mf] = *(const short8v*)&Ah[wr * 64 + mf * 16 + l15][lk];
      al[mf] = *(const short8v*)&Al[wr * 64 + mf * 16 + l15][lk];
    }
#pragma unroll
    for (int nf = 0; nf < 2; ++nf) {
      int oo = wc * 32 + nf * 16 + l15;
      bah[nf] = *(const short8v*)&Bw[0][oo][lk];
      bal[nf] = *(const short8v*)&Bw[1][oo][lk];
      bdh[nf] = *(const short8v*)&Bw[2][oo][lk];
      bdl[nf] = *(const short8v*)&Bw[3][oo][lk];
    }
#pragma unroll
    for (int mf = 0; mf < 4; ++mf)
#pragma unroll
      for (int nf = 0; nf < 2; ++nf) {
        accG[mf][nf] = __builtin_amdgcn_mfma_f32_16x16x32_bf16(
            ah[mf], bah[nf], accG[mf][nf], 0, 0, 0);
        accG[mf][nf] = __builtin_amdgcn_mfma_f32_16x16x32_bf16(
            ah[mf], bal[nf], accG[mf][nf], 0, 0, 0);
        accG[mf][nf] = __builtin_amdgcn_mfma_f32_16x16x32_bf16(
            al[mf], bah[nf], accG[mf][nf], 0, 0, 0);
        accC[mf][nf] = __builtin_amdgcn_mfma_f32_16x16x32_bf16(
            ah[mf], bdh[nf], accC[mf][nf], 0, 0, 0);
        accC[mf][nf] = __builtin_amdgcn_mfma_f32_16x16x32_bf16(
            ah[mf], bdl[nf], accC[mf][nf], 0, 0, 0);
        accC[mf][nf] = __builtin_amdgcn_mfma_f32_16x16x32_bf16(
            al[mf], bdh[nf], accC[mf][nf], 0, 0, 0);
      }
    __syncthreads();
  }
  float sh[2];
  sh[0] = bsh[o0 + wc * 32 + l15];
  sh[1] = bsh[o0 + wc * 32 + 16 + l15];
#pragma unroll
  for (int mf = 0; mf < 4; ++mf)
#pragma unroll
    for (int nf = 0; nf < 2; ++nf) {
      int col = o0 + wc * 32 + nf * 16 + l15;
#pragma unroll
      for (int r = 0; r < 4; ++r) {
        int row = base + wr * 64 + mf * 16 + (lane >> 4) * 4 + r;
        G[(size_t)row * CO + col] = accG[mf][nf][r];
        C[(size_t)row * CO + col] = accC[mf][nf][r] + sh[nf];
      }
    }
}

// ------- gather + leaky + max over k; emits bf16 hi/lo feature split -------
template <int CO>
__global__ __launch_bounds__(256) void gatherbf_kernel(
    const float* __restrict__ G, const float* __restrict__ C,
    const int* __restrict__ idx, unsigned short* __restrict__ outHi,
    unsigned short* __restrict__ outLo) {
  constexpr int O4 = CO / 4;
  int gid = blockIdx.x * 256 + (int)threadIdx.x;
  int o4 = gid % O4;
  int bn = gid / O4;
  int b = bn >> 11;
  const int* ip = &idx[(size_t)bn * KNN_K];
  const float* Gb = G + (size_t)b * N * CO;
  float4 cv = *(const float4*)&C[(size_t)bn * CO + o4 * 4];
  float4 m = make_float4(-1e30f, -1e30f, -1e30f, -1e30f);
#pragma unroll
  for (int k = 0; k < KNN_K; ++k) {
    int nb = ip[k];
    float4 g = *(const float4*)&Gb[(size_t)nb * CO + o4 * 4];
    m.x = lrelu_max(m.x, g.x + cv.x);
    m.y = lrelu_max(m.y, g.y + cv.y);
    m.z = lrelu_max(m.z, g.z + cv.z);
    m.w = lrelu_max(m.w, g.w + cv.w);
  }
  ushort4 hi, lo;
  hi.x = f2bf(m.x); lo.x = f2bf(m.x - bf2f(hi.x));
  hi.y = f2bf(m.y); lo.y = f2bf(m.y - bf2f(hi.y));
  hi.z = f2bf(m.z); lo.z = f2bf(m.z - bf2f(hi.z));
  hi.w = f2bf(m.w); lo.w = f2bf(m.w - bf2f(hi.w));
  *(ushort4*)&outHi[(size_t)bn * CO + o4 * 4] = hi;
  *(ushort4*)&outLo[(size_t)bn * CO + o4 * 4] = lo;
}

// ---------------- last layer: gather + max over k, partial max over n ------
template <int CO>
__global__ __launch_bounds__(256) void gather_last_kernel(
    const float* __restrict__ G, const float* __restrict__ C,
    const int* __restrict__ idx, float* __restrict__ part) {
  constexpr int O4 = CO / 4;
  constexpr int PL = 256 / O4;
  constexpr int ITER = 128 / PL;
  int b = blockIdx.x >> 4;
  int chunk = blockIdx.x & 15;
  int tid = (int)threadIdx.x;
  int o4 = tid % O4;
  int pl = tid / O4;
  const float* Gb = G + (size_t)b * N * CO;
  float4 m = make_float4(-1e30f, -1e30f, -1e30f, -1e30f);
  for (int it = 0; it < ITER; ++it) {
    int n = chunk * 128 + it * PL + pl;
    size_t bn = (size_t)b * N + n;
    const int* ip = &idx[bn * KNN_K];
    float4 cv = *(const float4*)&C[bn * CO + o4 * 4];
#pragma unroll
    for (int k = 0; k < KNN_K; ++k) {
      int nb = ip[k];
      float4 g = *(const float4*)&Gb[(size_t)nb * CO + o4 * 4];
      m.x = lrelu_max(m.x, g.x + cv.x);
      m.y = lrelu_max(m.y, g.y + cv.y);
      m.z = lrelu_max(m.z, g.z + cv.z);
      m.w = lrelu_max(m.w, g.w + cv.w);
    }
  }
  __shared__ __align__(16) float4 red[256];
  red[tid] = m;
  __syncthreads();
  for (int s = 128; s >= O4; s >>= 1) {
    if (tid < s) {
      float4 a = red[tid], bb = red[tid + s];
      red[tid] = make_float4(fmaxf(a.x, bb.x), fmaxf(a.y, bb.y),
                             fmaxf(a.z, bb.z), fmaxf(a.w, bb.w));
    }
    __syncthreads();
  }
  if (tid < O4) {
    *(float4*)&part[((size_t)(b * 16 + chunk)) * CO + tid * 4] = red[tid];
  }
}

template <int CO>
__global__ __launch_bounds__(256) void reduce_kernel(const float* __restrict__ part,
                                                     float* __restrict__ out,
                                                     int ooff) {
  constexpr int O4 = CO / 4;
  int gid = blockIdx.x * 256 + (int)threadIdx.x;
  int b = gid / O4;
  int o4 = gid % O4;
  float4 m = make_float4(-1e30f, -1e30f, -1e30f, -1e30f);
  for (int ch = 0; ch < 16; ++ch) {
    float4 v = *(const float4*)&part[((size_t)(b * 16 + ch)) * CO + o4 * 4];
    m.x = fmaxf(m.x, v.x); m.y = fmaxf(m.y, v.y);
    m.z = fmaxf(m.z, v.z); m.w = fmaxf(m.w, v.w);
  }
  *(float4*)&out[(size_t)b * 256 + ooff + o4 * 4] = m;
}

extern "C" void kernel_launch(void* const* d_in, const int* in_sizes, int n_in,
                              void* d_out, int out_size, void* d_ws, size_t ws_size,
                              hipStream_t stream) {
  const float* xyz = (const float*)d_in[0];
  const float* W0 = (const float*)d_in[1];
  const float* s0 = (const float*)d_in[2];
  const float* b0 = (const float*)d_in[3];
  const float* W1 = (const float*)d_in[4];
  const float* s1 = (const float*)d_in[5];
  const float* b1 = (const float*)d_in[6];
  const float* W2 = (const float*)d_in[7];
  const float* s2 = (const float*)d_in[8];
  const float* b2 = (const float*)d_in[9];
  float* out = (float*)d_out;

  const size_t MB = 1024 * 1024;
  char* ws = (char*)d_ws;
  int* idx = (int*)ws;                                        // 2 MB
  unsigned short* FHi = (unsigned short*)(ws + 2 * MB);       // 16 MB (M x <=128 bf16)
  unsigned short* FLo = (unsigned short*)(ws + 18 * MB);      // 16 MB
  float* G = (float*)(ws + 34 * MB);                          // 32 MB
  float* Cb = (float*)(ws + 66 * MB);                         // 32 MB
  unsigned short* wbuf = (unsigned short*)(ws + 98 * MB);     // 256 KB
  float* part = (float*)(ws + 98 * MB + 256 * 1024);          // 256 KB

  knn_kernel<<<B * 32, 256, 0, stream>>>(xyz, idx);

  // Layer 1: ci=3 (pad 4), co=64 — f32 path, output split to bf16 hi/lo
  transform_kernel<4, 64><<<dim3(M / 64, 1), 256, 0, stream>>>(xyz, W0, s0, b0, G, Cb);
  gatherbf_kernel<64><<<M * 16 / 256, 256, 0, stream>>>(G, Cb, idx, FHi, FLo);

  // Layer 2: K=64, CO=128 — MFMA 3-pass bf16 split
  wprep_kernel<64, 128><<<(64 * 128 + 255) / 256, 256, 0, stream>>>(W1, s1, wbuf);
  mfma_transform_kernel<64, 128><<<dim3(M / 128, 2), 256, 0, stream>>>(
      FHi, FLo, wbuf, b1, G, Cb, (size_t)64 * 128);
  gatherbf_kernel<128><<<M * 32 / 256, 256, 0, stream>>>(G, Cb, idx, FHi, FLo);

  // Layer 3: K=128, CO=256 in two 128-channel halves — MFMA
  wprep_kernel<128, 256><<<(128 * 256 + 255) / 256, 256, 0, stream>>>(W2, s2, wbuf);
  for (int h = 0; h < 2; ++h) {
    mfma_transform_kernel<128, 128><<<dim3(M / 128, 2), 256, 0, stream>>>(
        FHi, FLo, wbuf + (size_t)h * 128 * 128, b2 + h * 128, G, Cb,
        (size_t)128 * 256);
    gather_last_kernel<128><<<B * 16, 256, 0, stream>>>(G, Cb, idx, part);
    reduce_kernel<128><<<B * 128 / 4 / 256, 256, 0, stream>>>(part, out, h * 128);
  }
}

// Round 12
// 345.016 us; speedup vs baseline: 1.0847x; 1.0170x over previous
//
#include <hip/hip_runtime.h>

#define KNN_K 8
constexpr int B = 32;
constexpr int N = 2048;
constexpr int M = B * N;  // 65536 points

typedef __attribute__((ext_vector_type(8))) short short8v;  // 8 bf16
typedef __attribute__((ext_vector_type(4))) float f32x4;

__device__ __forceinline__ float lrelu_max(float m, float y) {
  return fmaxf(m, fmaxf(y, 0.2f * y));
}
__device__ __forceinline__ unsigned short f2bf(float x) {  // RNE f32->bf16
  unsigned int u = __float_as_uint(x);
  unsigned int r = u + 0x7FFFu + ((u >> 16) & 1u);
  return (unsigned short)(r >> 16);
}
__device__ __forceinline__ float bf2f(unsigned short h) {
  return __uint_as_float(((unsigned int)h) << 16);
}

// ---------------- KNN on reshape(xyz,(B,3,N)) pseudo-points ----------------
// 4 threads/query, interleaved quarters. Deferred selection in registers,
// 4-deep shift-in queue. Key encode exploits pd <= 0: mono = ~bits(pd) is
// order-preserving there and maps the self candidate (+0.0) to 0xFFFFFFFF
// (the max — exactly top_k's placement). Key low word ~m kept by induction.

#define CAS_T(i, j)                                        \
  {                                                        \
    unsigned long long _x = t[i], _y = t[j];               \
    bool _p = _x < _y;                                     \
    t[i] = _p ? _y : _x;                                   \
    t[j] = _p ? _x : _y;                                   \
  }
#define CAS_TOP(i, j)                                      \
  {                                                        \
    unsigned long long _x = top[i], _y = top[j];           \
    bool _p = _x < _y;                                     \
    top[i] = _p ? _y : _x;                                 \
    top[j] = _p ? _x : _y;                                 \
  }

__global__ __launch_bounds__(256) void knn_kernel(const float* __restrict__ xyz,
                                                  int* __restrict__ idx) {
  __shared__ __align__(16) float4 spt[N];  // 32 KB; reused as merge scratch
  int b = blockIdx.x >> 5;     // 32 blocks per batch
  int nblk = blockIdx.x & 31;  // 64 queries per block
  const float* F = xyz + (size_t)b * N * 3;
  for (int i = threadIdx.x; i < N; i += 256) {
    float x = F[i], y = F[N + i], z = F[2 * N + i];
    spt[i] = make_float4(x, y, z, (x * x + y * y) + z * z);
  }
  __syncthreads();
  const int tid = (int)threadIdx.x;
  const int ln = tid >> 2;  // 0..63 local query
  const int q = tid & 3;    // quarter
  const int n = nblk * 64 + ln;
  float4 pn = spt[n];
  const float npnw = -pn.w;

  unsigned long long top[8];   // sorted desc u64 keys; 0 = empty
  unsigned long long bufr[4];  // 4-deep shift-in queue; entries >= cnt stale
#pragma unroll
  for (int k = 0; k < 8; ++k) top[k] = 0ull;
#pragma unroll
  for (int k = 0; k < 4; ++k) bufr[k] = 0ull;
  float thr = -1e30f;
  int cnt = 0;

  auto flush = [&]() {
    unsigned long long t[4];
#pragma unroll
    for (int i = 0; i < 4; ++i) t[i] = (i < cnt) ? bufr[i] : 0ull;
    // sort 4 desc (5 CAS)
    CAS_T(0, 1) CAS_T(2, 3) CAS_T(0, 2) CAS_T(1, 3) CAS_T(1, 2)
    // bitonic half-clean vs zero-padded reversed t: only tail touched
    {
      unsigned long long x;
      x = top[4]; top[4] = x > t[3] ? x : t[3];
      x = top[5]; top[5] = x > t[2] ? x : t[2];
      x = top[6]; top[6] = x > t[1] ? x : t[1];
      x = top[7]; top[7] = x > t[0] ? x : t[0];
    }
    // bitonic clean 8 desc (12 CAS)
    CAS_TOP(0, 4) CAS_TOP(1, 5) CAS_TOP(2, 6) CAS_TOP(3, 7)
    CAS_TOP(0, 2) CAS_TOP(1, 3) CAS_TOP(4, 6) CAS_TOP(5, 7)
    CAS_TOP(0, 1) CAS_TOP(2, 3) CAS_TOP(4, 5) CAS_TOP(6, 7)
    cnt = 0;
    if (top[7] != 0ull) {  // guard: while not full, keep thr=-1e30 (accept all)
      thr = __uint_as_float(~(unsigned int)(top[7] >> 32));
    }
  };

  unsigned int mnot = ~(unsigned int)q;  // ~m, maintained by induction (-4/iter)
#pragma unroll 4
  for (int j = 0; j < N / 4; ++j) {
    int m = (j << 2) | q;
    float4 pm = spt[m];
    float dot = (pn.x * pm.x + pn.y * pm.y) + pn.z * pm.z;
    float pd = __builtin_fmaf(2.0f, dot, npnw) - pm.w;  // == -pn.w -(-2dot) -pm.w
    if (pd > thr) {  // strict: ties keep the earlier (lower) index, as top_k
      unsigned long long key =
          ((unsigned long long)(~__float_as_uint(pd)) << 32) |
          (unsigned long long)mnot;
      bufr[3] = bufr[2]; bufr[2] = bufr[1]; bufr[1] = bufr[0];
      bufr[0] = key;
      ++cnt;
    }
    mnot -= 4u;
    if (__any(cnt >= 4)) flush();
  }
  flush();  // drain partial queues

  __syncthreads();  // all scans done; safe to overwrite spt
  unsigned long long* km = (unsigned long long*)spt;  // [256][8] = 16 KB
#pragma unroll
  for (int k = 0; k < 8; ++k) km[tid * 8 + k] = top[k];
  __syncthreads();
  if (q == 0) {
    int h[4] = {0, 0, 0, 0};
    int* op = idx + ((size_t)b * N + n) * KNN_K;
#pragma unroll
    for (int k = 0; k < KNN_K; ++k) {
      unsigned long long bk = 0ull;
      int bq = 0;
#pragma unroll
      for (int qq = 0; qq < 4; ++qq) {
        unsigned long long kk = km[(((ln << 2) | qq)) * 8 + h[qq]];
        if (kk > bk) { bk = kk; bq = qq; }
      }
      op[k] = (int)(0xFFFFFFFFu - (unsigned int)(bk & 0xFFFFFFFFull));
      h[bq]++;
    }
  }
}

// ---------------- layer-1 transform (tiny K): f32 VALU path ----------------
template <int CI, int CO>
__global__ __launch_bounds__(256) void transform_kernel(
    const float* __restrict__ f, const float* __restrict__ W,
    const float* __restrict__ s, const float* __restrict__ bsh,
    float* __restrict__ G, float* __restrict__ C) {
  constexpr int KC = CI;  // CI == 4 only
  __shared__ __align__(16) float fs[KC][68];
  __shared__ __align__(16) float was[KC][68];
  __shared__ __align__(16) float wds[KC][68];
  const int base = blockIdx.x * 64;
  const int o0 = blockIdx.y * 64;
  const int tid = threadIdx.x;
  const int tx = tid & 15, ty = tid >> 4;
  float accG[4][4] = {{0}};
  float accC[4][4] = {{0}};
  for (int i = tid; i < 64 * 4; i += 256) {
    int c = i & 3, p = i >> 2;
    fs[c][p] = (c < 3) ? f[(size_t)(base + p) * 3 + c] : 0.0f;
  }
  if (tid < 64) {
    int o = tid;
    float sc = s[o0 + o];
    const float* wr = &W[(size_t)(o0 + o) * 6];
#pragma unroll
    for (int c = 0; c < 4; ++c) {
      float wa = (c < 3) ? wr[c] : 0.0f;
      float wb = (c < 3) ? wr[3 + c] : 0.0f;
      was[c][o] = sc * wa;
      wds[c][o] = sc * (wb - wa);
    }
  }
  __syncthreads();
#pragma unroll
  for (int c = 0; c < KC; ++c) {
    float4 av = *(const float4*)&fs[c][ty * 4];
    float4 wg = *(const float4*)&was[c][tx * 4];
    float4 wd = *(const float4*)&wds[c][tx * 4];
    float a[4] = {av.x, av.y, av.z, av.w};
    float g[4] = {wg.x, wg.y, wg.z, wg.w};
    float d[4] = {wd.x, wd.y, wd.z, wd.w};
#pragma unroll
    for (int i = 0; i < 4; ++i)
#pragma unroll
      for (int j = 0; j < 4; ++j) {
        accG[i][j] = fmaf(a[i], g[j], accG[i][j]);
        accC[i][j] = fmaf(a[i], d[j], accC[i][j]);
      }
  }
  float4 sh = *(const float4*)&bsh[o0 + tx * 4];
  float shv[4] = {sh.x, sh.y, sh.z, sh.w};
#pragma unroll
  for (int i = 0; i < 4; ++i) {
    size_t row = (size_t)(base + ty * 4 + i);
    float4 g4 = make_float4(accG[i][0], accG[i][1], accG[i][2], accG[i][3]);
    float4 c4 = make_float4(accC[i][0] + shv[0], accC[i][1] + shv[1],
                            accC[i][2] + shv[2], accC[i][3] + shv[3]);
    *(float4*)&G[row * CO + o0 + tx * 4] = g4;
    *(float4*)&C[row * CO + o0 + tx * 4] = c4;
  }
}

// ------------- weight prep: split s*Wa, s*(Wb-Wa) into bf16 hi/lo ----------
template <int CI, int CO>
__global__ __launch_bounds__(256) void wprep_kernel(
    const float* __restrict__ W, const float* __restrict__ s,
    unsigned short* __restrict__ wb) {
  int i = blockIdx.x * 256 + (int)threadIdx.x;  // o*CI + k
  if (i >= CI * CO) return;
  int o = i / CI, k = i % CI;
  float sc = s[o];
  float w0 = W[(size_t)o * 2 * CI + k];
  float wa = sc * w0;
  float wd = sc * (W[(size_t)o * 2 * CI + CI + k] - w0);
  unsigned short waH = f2bf(wa);
  unsigned short waL = f2bf(wa - bf2f(waH));
  unsigned short wdH = f2bf(wd);
  unsigned short wdL = f2bf(wd - bf2f(wdH));
  wb[i] = waH;
  wb[CI * CO + i] = waL;
  wb[2 * CI * CO + i] = wdH;
  wb[3 * CI * CO + i] = wdL;
}

// --------- MFMA transform: G/C = A(hi+lo) @ W(hi+lo), 3-pass bf16 ---------
// tile 128 pts x 64 outs, 4 waves (2x2), wave tile 64x32; K-chunks of 32.
template <int K, int CO>
__global__ __launch_bounds__(256) void mfma_transform_kernel(
    const unsigned short* __restrict__ AHi, const unsigned short* __restrict__ ALo,
    const unsigned short* __restrict__ wb, const float* __restrict__ bsh,
    float* __restrict__ G, float* __restrict__ C, size_t arrStride) {
  constexpr int KP = 40;  // padded LDS k-stride (bf16) -> 80B rows, no 8-way conflict
  __shared__ unsigned short Ah[128][KP];
  __shared__ unsigned short Al[128][KP];
  __shared__ unsigned short Bw[4][64][KP];
  const int base = blockIdx.x * 128;
  const int o0 = blockIdx.y * 64;
  const int tid = (int)threadIdx.x;
  const int lane = tid & 63;
  const int wid = tid >> 6;
  const int wr = wid >> 1;  // wave row-half (64 pts)
  const int wc = wid & 1;   // wave col-half (32 outs)
  const int l15 = lane & 15;
  const int lk = (lane >> 4) * 8;  // fragment k-base

  f32x4 zero = {0.f, 0.f, 0.f, 0.f};
  f32x4 accG[4][2], accC[4][2];
#pragma unroll
  for (int i = 0; i < 4; ++i)
#pragma unroll
    for (int j = 0; j < 2; ++j) { accG[i][j] = zero; accC[i][j] = zero; }

  const int arow = tid >> 1;        // 0..127
  const int akh = (tid & 1) * 16;   // 0 / 16
  const int bo = tid & 63;          // weight out-row
  const int barr = tid >> 6;        // which of 4 arrays

  for (int kc0 = 0; kc0 < K; kc0 += 32) {
    {  // stage A hi/lo: 128 x 32 bf16 each
      const unsigned short* pa = &AHi[(size_t)(base + arow) * K + kc0 + akh];
      short8v h0 = *(const short8v*)pa;
      short8v h1 = *(const short8v*)(pa + 8);
      *(short8v*)&Ah[arow][akh] = h0;
      *(short8v*)&Ah[arow][akh + 8] = h1;
      const unsigned short* pl = &ALo[(size_t)(base + arow) * K + kc0 + akh];
      short8v l0 = *(const short8v*)pl;
      short8v l1 = *(const short8v*)(pl + 8);
      *(short8v*)&Al[arow][akh] = l0;
      *(short8v*)&Al[arow][akh + 8] = l1;
      // stage B: 4 arrays x 64 outs x 32 k
      const unsigned short* pb =
          &wb[(size_t)barr * arrStride + (size_t)(o0 + bo) * K + kc0];
#pragma unroll
      for (int j = 0; j < 4; ++j) {
        short8v v = *(const short8v*)(pb + j * 8);
        *(short8v*)&Bw[barr][bo][j * 8] = v;
      }
    }
    __syncthreads();
    short8v ah[4], al[4], bah[2], bal[2], bdh[2], bdl[2];
#pragma unroll
    for (int mf = 0; mf < 4; ++mf) {
      ah[mf] = *(const short8v*)&Ah[wr * 64 + mf * 16 + l15][lk];
      al[mf] = *(const short8v*)&Al[wr * 64 + mf * 16 + l15][lk];
    }
#pragma unroll
    for (int nf = 0; nf < 2; ++nf) {
      int oo = wc * 32 + nf * 16 + l15;
      bah[nf] = *(const short8v*)&Bw[0][oo][lk];
      bal[nf] = *(const short8v*)&Bw[1][oo][lk];
      bdh[nf] = *(const short8v*)&Bw[2][oo][lk];
      bdl[nf] = *(const short8v*)&Bw[3][oo][lk];
    }
#pragma unroll
    for (int mf = 0; mf < 4; ++mf)
#pragma unroll
      for (int nf = 0; nf < 2; ++nf) {
        accG[mf][nf] = __builtin_amdgcn_mfma_f32_16x16x32_bf16(
            ah[mf], bah[nf], accG[mf][nf], 0, 0, 0);
        accG[mf][nf] = __builtin_amdgcn_mfma_f32_16x16x32_bf16(
            ah[mf], bal[nf], accG[mf][nf], 0, 0, 0);
        accG[mf][nf] = __builtin_amdgcn_mfma_f32_16x16x32_bf16(
            al[mf], bah[nf], accG[mf][nf], 0, 0, 0);
        accC[mf][nf] = __builtin_amdgcn_mfma_f32_16x16x32_bf16(
            ah[mf], bdh[nf], accC[mf][nf], 0, 0, 0);
        accC[mf][nf] = __builtin_amdgcn_mfma_f32_16x16x32_bf16(
            ah[mf], bdl[nf], accC[mf][nf], 0, 0, 0);
        accC[mf][nf] = __builtin_amdgcn_mfma_f32_16x16x32_bf16(
            al[mf], bdh[nf], accC[mf][nf], 0, 0, 0);
      }
    __syncthreads();
  }
  float sh[2];
  sh[0] = bsh[o0 + wc * 32 + l15];
  sh[1] = bsh[o0 + wc * 32 + 16 + l15];
#pragma unroll
  for (int mf = 0; mf < 4; ++mf)
#pragma unroll
    for (int nf = 0; nf < 2; ++nf) {
      int col = o0 + wc * 32 + nf * 16 + l15;
#pragma unroll
      for (int r = 0; r < 4; ++r) {
        int row = base + wr * 64 + mf * 16 + (lane >> 4) * 4 + r;
        G[(size_t)row * CO + col] = accG[mf][nf][r];
        C[(size_t)row * CO + col] = accC[mf][nf][r] + sh[nf];
      }
    }
}

// ------- gather + leaky + max over k; emits bf16 hi/lo feature split -------
template <int CO>
__global__ __launch_bounds__(256) void gatherbf_kernel(
    const float* __restrict__ G, const float* __restrict__ C,
    const int* __restrict__ idx, unsigned short* __restrict__ outHi,
    unsigned short* __restrict__ outLo) {
  constexpr int O4 = CO / 4;
  int gid = blockIdx.x * 256 + (int)threadIdx.x;
  int o4 = gid % O4;
  int bn = gid / O4;
  int b = bn >> 11;
  const int* ip = &idx[(size_t)bn * KNN_K];
  const float* Gb = G + (size_t)b * N * CO;
  float4 cv = *(const float4*)&C[(size_t)bn * CO + o4 * 4];
  float4 m = make_float4(-1e30f, -1e30f, -1e30f, -1e30f);
#pragma unroll
  for (int k = 0; k < KNN_K; ++k) {
    int nb = ip[k];
    float4 g = *(const float4*)&Gb[(size_t)nb * CO + o4 * 4];
    m.x = lrelu_max(m.x, g.x + cv.x);
    m.y = lrelu_max(m.y, g.y + cv.y);
    m.z = lrelu_max(m.z, g.z + cv.z);
    m.w = lrelu_max(m.w, g.w + cv.w);
  }
  ushort4 hi, lo;
  hi.x = f2bf(m.x); lo.x = f2bf(m.x - bf2f(hi.x));
  hi.y = f2bf(m.y); lo.y = f2bf(m.y - bf2f(hi.y));
  hi.z = f2bf(m.z); lo.z = f2bf(m.z - bf2f(hi.z));
  hi.w = f2bf(m.w); lo.w = f2bf(m.w - bf2f(hi.w));
  *(ushort4*)&outHi[(size_t)bn * CO + o4 * 4] = hi;
  *(ushort4*)&outLo[(size_t)bn * CO + o4 * 4] = lo;
}

// ---------------- last layer: gather + max over k, partial max over n ------
template <int CO>
__global__ __launch_bounds__(256) void gather_last_kernel(
    const float* __restrict__ G, const float* __restrict__ C,
    const int* __restrict__ idx, float* __restrict__ part) {
  constexpr int O4 = CO / 4;
  constexpr int PL = 256 / O4;
  constexpr int ITER = 128 / PL;
  int b = blockIdx.x >> 4;
  int chunk = blockIdx.x & 15;
  int tid = (int)threadIdx.x;
  int o4 = tid % O4;
  int pl = tid / O4;
  const float* Gb = G + (size_t)b * N * CO;
  float4 m = make_float4(-1e30f, -1e30f, -1e30f, -1e30f);
  for (int it = 0; it < ITER; ++it) {
    int n = chunk * 128 + it * PL + pl;
    size_t bn = (size_t)b * N + n;
    const int* ip = &idx[bn * KNN_K];
    float4 cv = *(const float4*)&C[bn * CO + o4 * 4];
#pragma unroll
    for (int k = 0; k < KNN_K; ++k) {
      int nb = ip[k];
      float4 g = *(const float4*)&Gb[(size_t)nb * CO + o4 * 4];
      m.x = lrelu_max(m.x, g.x + cv.x);
      m.y = lrelu_max(m.y, g.y + cv.y);
      m.z = lrelu_max(m.z, g.z + cv.z);
      m.w = lrelu_max(m.w, g.w + cv.w);
    }
  }
  __shared__ __align__(16) float4 red[256];
  red[tid] = m;
  __syncthreads();
  for (int s = 128; s >= O4; s >>= 1) {
    if (tid < s) {
      float4 a = red[tid], bb = red[tid + s];
      red[tid] = make_float4(fmaxf(a.x, bb.x), fmaxf(a.y, bb.y),
                             fmaxf(a.z, bb.z), fmaxf(a.w, bb.w));
    }
    __syncthreads();
  }
  if (tid < O4) {
    *(float4*)&part[((size_t)(b * 16 + chunk)) * CO + tid * 4] = red[tid];
  }
}

// --------- fused final reduce over both 128-channel halves (grid.y=2) ------
template <int CO>
__global__ __launch_bounds__(256) void reduce2_kernel(const float* __restrict__ part,
                                                      float* __restrict__ out) {
  constexpr int O4 = CO / 4;
  int half = blockIdx.y;
  const float* p = part + (size_t)half * B * 16 * CO;
  int gid = blockIdx.x * 256 + (int)threadIdx.x;  // 0 .. B*O4-1
  int b = gid / O4;
  int o4 = gid % O4;
  float4 m = make_float4(-1e30f, -1e30f, -1e30f, -1e30f);
  for (int ch = 0; ch < 16; ++ch) {
    float4 v = *(const float4*)&p[((size_t)(b * 16 + ch)) * CO + o4 * 4];
    m.x = fmaxf(m.x, v.x); m.y = fmaxf(m.y, v.y);
    m.z = fmaxf(m.z, v.z); m.w = fmaxf(m.w, v.w);
  }
  *(float4*)&out[(size_t)b * 256 + half * 128 + o4 * 4] = m;
}

extern "C" void kernel_launch(void* const* d_in, const int* in_sizes, int n_in,
                              void* d_out, int out_size, void* d_ws, size_t ws_size,
                              hipStream_t stream) {
  const float* xyz = (const float*)d_in[0];
  const float* W0 = (const float*)d_in[1];
  const float* s0 = (const float*)d_in[2];
  const float* b0 = (const float*)d_in[3];
  const float* W1 = (const float*)d_in[4];
  const float* s1 = (const float*)d_in[5];
  const float* b1 = (const float*)d_in[6];
  const float* W2 = (const float*)d_in[7];
  const float* s2 = (const float*)d_in[8];
  const float* b2 = (const float*)d_in[9];
  float* out = (float*)d_out;

  const size_t MB = 1024 * 1024;
  char* ws = (char*)d_ws;
  int* idx = (int*)ws;                                        // 2 MB
  unsigned short* FHi = (unsigned short*)(ws + 2 * MB);       // 16 MB (M x <=128 bf16)
  unsigned short* FLo = (unsigned short*)(ws + 18 * MB);      // 16 MB
  float* G = (float*)(ws + 34 * MB);                          // 32 MB
  float* Cb = (float*)(ws + 66 * MB);                         // 32 MB
  unsigned short* wbuf = (unsigned short*)(ws + 98 * MB);     // 256 KB
  float* part = (float*)(ws + 98 * MB + 256 * 1024);          // 512 KB (2 halves)

  knn_kernel<<<B * 32, 256, 0, stream>>>(xyz, idx);

  // Layer 1: ci=3 (pad 4), co=64 — f32 path, output split to bf16 hi/lo
  transform_kernel<4, 64><<<dim3(M / 64, 1), 256, 0, stream>>>(xyz, W0, s0, b0, G, Cb);
  gatherbf_kernel<64><<<M * 16 / 256, 256, 0, stream>>>(G, Cb, idx, FHi, FLo);

  // Layer 2: K=64, CO=128 — MFMA 3-pass bf16 split
  wprep_kernel<64, 128><<<(64 * 128 + 255) / 256, 256, 0, stream>>>(W1, s1, wbuf);
  mfma_transform_kernel<64, 128><<<dim3(M / 128, 2), 256, 0, stream>>>(
      FHi, FLo, wbuf, b1, G, Cb, (size_t)64 * 128);
  gatherbf_kernel<128><<<M * 32 / 256, 256, 0, stream>>>(G, Cb, idx, FHi, FLo);

  // Layer 3: K=128, CO=256 in two 128-channel halves — MFMA
  wprep_kernel<128, 256><<<(128 * 256 + 255) / 256, 256, 0, stream>>>(W2, s2, wbuf);
  for (int h = 0; h < 2; ++h) {
    mfma_transform_kernel<128, 128><<<dim3(M / 128, 2), 256, 0, stream>>>(
        FHi, FLo, wbuf + (size_t)h * 128 * 128, b2 + h * 128, G, Cb,
        (size_t)128 * 256);
    gather_last_kernel<128><<<B * 16, 256, 0, stream>>>(
        G, Cb, idx, part + (size_t)h * B * 16 * 128);
  }
  reduce2_kernel<128><<<dim3(B * 128 / 4 / 256, 2), 256, 0, stream>>>(part, out);
}

// Round 13
// 285.648 us; speedup vs baseline: 1.3102x; 1.2078x over previous
//
#include <hip/hip_runtime.h>

#define KNN_K 8
constexpr int B = 32;
constexpr int N = 2048;
constexpr int M = B * N;  // 65536 points

typedef __attribute__((ext_vector_type(8))) short short8v;  // 8 bf16
typedef __attribute__((ext_vector_type(4))) float f32x4;

__device__ __forceinline__ float lrelu_max(float m, float y) {
  return fmaxf(m, fmaxf(y, 0.2f * y));
}
__device__ __forceinline__ unsigned short f2bf(float x) {  // RNE f32->bf16
  unsigned int u = __float_as_uint(x);
  unsigned int r = u + 0x7FFFu + ((u >> 16) & 1u);
  return (unsigned short)(r >> 16);
}
__device__ __forceinline__ float bf2f(unsigned short h) {
  return __uint_as_float(((unsigned int)h) << 16);
}

// ---------------- KNN on reshape(xyz,(B,3,N)) pseudo-points ----------------
// 4 threads/query, interleaved quarters. Deferred selection in registers,
// 4-deep shift-in queue. Key encode exploits pd <= 0: mono = ~bits(pd).

#define CAS_T(i, j)                                        \
  {                                                        \
    unsigned long long _x = t[i], _y = t[j];               \
    bool _p = _x < _y;                                     \
    t[i] = _p ? _y : _x;                                   \
    t[j] = _p ? _x : _y;                                   \
  }
#define CAS_TOP(i, j)                                      \
  {                                                        \
    unsigned long long _x = top[i], _y = top[j];           \
    bool _p = _x < _y;                                     \
    top[i] = _p ? _y : _x;                                 \
    top[j] = _p ? _x : _y;                                 \
  }

__global__ __launch_bounds__(256) void knn_kernel(const float* __restrict__ xyz,
                                                  int* __restrict__ idx) {
  __shared__ __align__(16) float4 spt[N];  // 32 KB; reused as merge scratch
  int b = blockIdx.x >> 5;     // 32 blocks per batch
  int nblk = blockIdx.x & 31;  // 64 queries per block
  const float* F = xyz + (size_t)b * N * 3;
  for (int i = threadIdx.x; i < N; i += 256) {
    float x = F[i], y = F[N + i], z = F[2 * N + i];
    spt[i] = make_float4(x, y, z, (x * x + y * y) + z * z);
  }
  __syncthreads();
  const int tid = (int)threadIdx.x;
  const int ln = tid >> 2;  // 0..63 local query
  const int q = tid & 3;    // quarter
  const int n = nblk * 64 + ln;
  float4 pn = spt[n];
  const float npnw = -pn.w;

  unsigned long long top[8];   // sorted desc u64 keys; 0 = empty
  unsigned long long bufr[4];  // 4-deep shift-in queue; entries >= cnt stale
#pragma unroll
  for (int k = 0; k < 8; ++k) top[k] = 0ull;
#pragma unroll
  for (int k = 0; k < 4; ++k) bufr[k] = 0ull;
  float thr = -1e30f;
  int cnt = 0;

  auto flush = [&]() {
    unsigned long long t[4];
#pragma unroll
    for (int i = 0; i < 4; ++i) t[i] = (i < cnt) ? bufr[i] : 0ull;
    // sort 4 desc (5 CAS)
    CAS_T(0, 1) CAS_T(2, 3) CAS_T(0, 2) CAS_T(1, 3) CAS_T(1, 2)
    // bitonic half-clean vs zero-padded reversed t: only tail touched
    {
      unsigned long long x;
      x = top[4]; top[4] = x > t[3] ? x : t[3];
      x = top[5]; top[5] = x > t[2] ? x : t[2];
      x = top[6]; top[6] = x > t[1] ? x : t[1];
      x = top[7]; top[7] = x > t[0] ? x : t[0];
    }
    // bitonic clean 8 desc (12 CAS)
    CAS_TOP(0, 4) CAS_TOP(1, 5) CAS_TOP(2, 6) CAS_TOP(3, 7)
    CAS_TOP(0, 2) CAS_TOP(1, 3) CAS_TOP(4, 6) CAS_TOP(5, 7)
    CAS_TOP(0, 1) CAS_TOP(2, 3) CAS_TOP(4, 5) CAS_TOP(6, 7)
    cnt = 0;
    if (top[7] != 0ull) {  // guard: while not full, keep thr=-1e30 (accept all)
      thr = __uint_as_float(~(unsigned int)(top[7] >> 32));
    }
  };

  unsigned int mnot = ~(unsigned int)q;  // ~m, maintained by induction (-4/iter)
#pragma unroll 4
  for (int j = 0; j < N / 4; ++j) {
    int m = (j << 2) | q;
    float4 pm = spt[m];
    float dot = (pn.x * pm.x + pn.y * pm.y) + pn.z * pm.z;
    float pd = __builtin_fmaf(2.0f, dot, npnw) - pm.w;  // == -pn.w -(-2dot) -pm.w
    if (pd > thr) {  // strict: ties keep the earlier (lower) index, as top_k
      unsigned long long key =
          ((unsigned long long)(~__float_as_uint(pd)) << 32) |
          (unsigned long long)mnot;
      bufr[3] = bufr[2]; bufr[2] = bufr[1]; bufr[1] = bufr[0];
      bufr[0] = key;
      ++cnt;
    }
    mnot -= 4u;
    if (__any(cnt >= 4)) flush();
  }
  flush();  // drain partial queues

  __syncthreads();  // all scans done; safe to overwrite spt
  unsigned long long* km = (unsigned long long*)spt;  // [256][8] = 16 KB
#pragma unroll
  for (int k = 0; k < 8; ++k) km[tid * 8 + k] = top[k];
  __syncthreads();
  if (q == 0) {
    int h[4] = {0, 0, 0, 0};
    int* op = idx + ((size_t)b * N + n) * KNN_K;
#pragma unroll
    for (int k = 0; k < KNN_K; ++k) {
      unsigned long long bk = 0ull;
      int bq = 0;
#pragma unroll
      for (int qq = 0; qq < 4; ++qq) {
        unsigned long long kk = km[(((ln << 2) | qq)) * 8 + h[qq]];
        if (kk > bk) { bk = kk; bq = qq; }
      }
      op[k] = (int)(0xFFFFFFFFu - (unsigned int)(bk & 0xFFFFFFFFull));
      h[bq]++;
    }
  }
}

// ---------------- layer-1 transform (tiny K): f32 VALU path ----------------
template <int CI, int CO>
__global__ __launch_bounds__(256) void transform_kernel(
    const float* __restrict__ f, const float* __restrict__ W,
    const float* __restrict__ s, const float* __restrict__ bsh,
    float* __restrict__ G, float* __restrict__ C) {
  constexpr int KC = CI;  // CI == 4 only
  __shared__ __align__(16) float fs[KC][68];
  __shared__ __align__(16) float was[KC][68];
  __shared__ __align__(16) float wds[KC][68];
  const int base = blockIdx.x * 64;
  const int o0 = blockIdx.y * 64;
  const int tid = threadIdx.x;
  const int tx = tid & 15, ty = tid >> 4;
  float accG[4][4] = {{0}};
  float accC[4][4] = {{0}};
  for (int i = tid; i < 64 * 4; i += 256) {
    int c = i & 3, p = i >> 2;
    fs[c][p] = (c < 3) ? f[(size_t)(base + p) * 3 + c] : 0.0f;
  }
  if (tid < 64) {
    int o = tid;
    float sc = s[o0 + o];
    const float* wr = &W[(size_t)(o0 + o) * 6];
#pragma unroll
    for (int c = 0; c < 4; ++c) {
      float wa = (c < 3) ? wr[c] : 0.0f;
      float wb = (c < 3) ? wr[3 + c] : 0.0f;
      was[c][o] = sc * wa;
      wds[c][o] = sc * (wb - wa);
    }
  }
  __syncthreads();
#pragma unroll
  for (int c = 0; c < KC; ++c) {
    float4 av = *(const float4*)&fs[c][ty * 4];
    float4 wg = *(const float4*)&was[c][tx * 4];
    float4 wd = *(const float4*)&wds[c][tx * 4];
    float a[4] = {av.x, av.y, av.z, av.w};
    float g[4] = {wg.x, wg.y, wg.z, wg.w};
    float d[4] = {wd.x, wd.y, wd.z, wd.w};
#pragma unroll
    for (int i = 0; i < 4; ++i)
#pragma unroll
      for (int j = 0; j < 4; ++j) {
        accG[i][j] = fmaf(a[i], g[j], accG[i][j]);
        accC[i][j] = fmaf(a[i], d[j], accC[i][j]);
      }
  }
  float4 sh = *(const float4*)&bsh[o0 + tx * 4];
  float shv[4] = {sh.x, sh.y, sh.z, sh.w};
#pragma unroll
  for (int i = 0; i < 4; ++i) {
    size_t row = (size_t)(base + ty * 4 + i);
    float4 g4 = make_float4(accG[i][0], accG[i][1], accG[i][2], accG[i][3]);
    float4 c4 = make_float4(accC[i][0] + shv[0], accC[i][1] + shv[1],
                            accC[i][2] + shv[2], accC[i][3] + shv[3]);
    *(float4*)&G[row * CO + o0 + tx * 4] = g4;
    *(float4*)&C[row * CO + o0 + tx * 4] = c4;
  }
}

// ------------- weight prep: split s*Wa, s*(Wb-Wa) into bf16 hi/lo ----------
template <int CI, int CO>
__global__ __launch_bounds__(256) void wprep_kernel(
    const float* __restrict__ W, const float* __restrict__ s,
    unsigned short* __restrict__ wb) {
  int i = blockIdx.x * 256 + (int)threadIdx.x;  // o*CI + k
  if (i >= CI * CO) return;
  int o = i / CI, k = i % CI;
  float sc = s[o];
  float w0 = W[(size_t)o * 2 * CI + k];
  float wa = sc * w0;
  float wd = sc * (W[(size_t)o * 2 * CI + CI + k] - w0);
  unsigned short waH = f2bf(wa);
  unsigned short waL = f2bf(wa - bf2f(waH));
  unsigned short wdH = f2bf(wd);
  unsigned short wdL = f2bf(wd - bf2f(wdH));
  wb[i] = waH;
  wb[CI * CO + i] = waL;
  wb[2 * CI * CO + i] = wdH;
  wb[3 * CI * CO + i] = wdL;
}

// --------- MFMA transform: G/C = A(hi+lo) @ W(hi+lo), 3-pass bf16 ---------
// tile 128 pts x 64 outs, 4 waves (2x2), wave tile 64x32; K-chunks of 32.
template <int K, int CO>
__global__ __launch_bounds__(256) void mfma_transform_kernel(
    const unsigned short* __restrict__ AHi, const unsigned short* __restrict__ ALo,
    const unsigned short* __restrict__ wb, const float* __restrict__ bsh,
    float* __restrict__ G, float* __restrict__ C, size_t arrStride) {
  constexpr int KP = 40;  // padded LDS k-stride (bf16) -> 80B rows, no 8-way conflict
  __shared__ unsigned short Ah[128][KP];
  __shared__ unsigned short Al[128][KP];
  __shared__ unsigned short Bw[4][64][KP];
  const int base = blockIdx.x * 128;
  const int o0 = blockIdx.y * 64;
  const int tid = (int)threadIdx.x;
  const int lane = tid & 63;
  const int wid = tid >> 6;
  const int wr = wid >> 1;  // wave row-half (64 pts)
  const int wc = wid & 1;   // wave col-half (32 outs)
  const int l15 = lane & 15;
  const int lk = (lane >> 4) * 8;  // fragment k-base

  f32x4 zero = {0.f, 0.f, 0.f, 0.f};
  f32x4 accG[4][2], accC[4][2];
#pragma unroll
  for (int i = 0; i < 4; ++i)
#pragma unroll
    for (int j = 0; j < 2; ++j) { accG[i][j] = zero; accC[i][j] = zero; }

  const int arow = tid >> 1;        // 0..127
  const int akh = (tid & 1) * 16;   // 0 / 16
  const int bo = tid & 63;          // weight out-row
  const int barr = tid >> 6;        // which of 4 arrays

  for (int kc0 = 0; kc0 < K; kc0 += 32) {
    {  // stage A hi/lo: 128 x 32 bf16 each
      const unsigned short* pa = &AHi[(size_t)(base + arow) * K + kc0 + akh];
      short8v h0 = *(const short8v*)pa;
      short8v h1 = *(const short8v*)(pa + 8);
      *(short8v*)&Ah[arow][akh] = h0;
      *(short8v*)&Ah[arow][akh + 8] = h1;
      const unsigned short* pl = &ALo[(size_t)(base + arow) * K + kc0 + akh];
      short8v l0 = *(const short8v*)pl;
      short8v l1 = *(const short8v*)(pl + 8);
      *(short8v*)&Al[arow][akh] = l0;
      *(short8v*)&Al[arow][akh + 8] = l1;
      // stage B: 4 arrays x 64 outs x 32 k
      const unsigned short* pb =
          &wb[(size_t)barr * arrStride + (size_t)(o0 + bo) * K + kc0];
#pragma unroll
      for (int j = 0; j < 4; ++j) {
        short8v v = *(const short8v*)(pb + j * 8);
        *(short8v*)&Bw[barr][bo][j * 8] = v;
      }
    }
    __syncthreads();
    short8v ah[4], al[4], bah[2], bal[2], bdh[2], bdl[2];
#pragma unroll
    for (int mf = 0; mf < 4; ++mf) {
      ah[mf] = *(const short8v*)&Ah[wr * 64 + mf * 16 + l15][lk];
      al[mf] = *(const short8v*)&Al[wr * 64 + mf * 16 + l15][lk];
    }
#pragma unroll
    for (int nf = 0; nf < 2; ++nf) {
      int oo = wc * 32 + nf * 16 + l15;
      bah[nf] = *(const short8v*)&Bw[0][oo][lk];
      bal[nf] = *(const short8v*)&Bw[1][oo][lk];
      bdh[nf] = *(const short8v*)&Bw[2][oo][lk];
      bdl[nf] = *(const short8v*)&Bw[3][oo][lk];
    }
#pragma unroll
    for (int mf = 0; mf < 4; ++mf)
#pragma unroll
      for (int nf = 0; nf < 2; ++nf) {
        accG[mf][nf] = __builtin_amdgcn_mfma_f32_16x16x32_bf16(
            ah[mf], bah[nf], accG[mf][nf], 0, 0, 0);
        accG[mf][nf] = __builtin_amdgcn_mfma_f32_16x16x32_bf16(
            ah[mf], bal[nf], accG[mf][nf], 0, 0, 0);
        accG[mf][nf] = __builtin_amdgcn_mfma_f32_16x16x32_bf16(
            al[mf], bah[nf], accG[mf][nf], 0, 0, 0);
        accC[mf][nf] = __builtin_amdgcn_mfma_f32_16x16x32_bf16(
            ah[mf], bdh[nf], accC[mf][nf], 0, 0, 0);
        accC[mf][nf] = __builtin_amdgcn_mfma_f32_16x16x32_bf16(
            ah[mf], bdl[nf], accC[mf][nf], 0, 0, 0);
        accC[mf][nf] = __builtin_amdgcn_mfma_f32_16x16x32_bf16(
            al[mf], bdh[nf], accC[mf][nf], 0, 0, 0);
      }
    __syncthreads();
  }
  float sh[2];
  sh[0] = bsh[o0 + wc * 32 + l15];
  sh[1] = bsh[o0 + wc * 32 + 16 + l15];
#pragma unroll
  for (int mf = 0; mf < 4; ++mf)
#pragma unroll
    for (int nf = 0; nf < 2; ++nf) {
      int col = o0 + wc * 32 + nf * 16 + l15;
#pragma unroll
      for (int r = 0; r < 4; ++r) {
        int row = base + wr * 64 + mf * 16 + (lane >> 4) * 4 + r;
        G[(size_t)row * CO + col] = accG[mf][nf][r];
        C[(size_t)row * CO + col] = accC[mf][nf][r] + sh[nf];
      }
    }
}

// ------- gather + leaky + max over k; emits bf16 hi/lo feature split -------
// XCD-locality: batches processed in 4 groups of 8; within a group,
// batch = g*8 + (blockIdx%8) so all blocks of a batch land on one XCD
// (blockIdx%8 == XCD round-robin) and G[b] stays L2-resident (T1 mechanism).
template <int CO>
__global__ __launch_bounds__(256) void gatherbf_kernel(
    const float* __restrict__ G, const float* __restrict__ C,
    const int* __restrict__ idx, unsigned short* __restrict__ outHi,
    unsigned short* __restrict__ outLo) {
  constexpr int O4 = CO / 4;
  constexpr int PPB = 256 / O4;        // points per block
  constexpr int BPB = N / PPB;         // blocks per batch
  constexpr int GRP = 8 * BPB;         // blocks per batch-group
  const int i = (int)blockIdx.x;
  const int g = i / GRP;
  const int j = i % GRP;
  const int b = g * 8 + (j & 7);
  const int chunk = j >> 3;
  const int tid = (int)threadIdx.x;
  const int o4 = tid % O4;
  const int lp = tid / O4;
  const size_t bn = (size_t)b * N + chunk * PPB + lp;
  const int* ip = &idx[bn * KNN_K];
  const float* Gb = G + (size_t)b * N * CO;
  float4 cv = *(const float4*)&C[bn * CO + o4 * 4];
  float4 m = make_float4(-1e30f, -1e30f, -1e30f, -1e30f);
#pragma unroll
  for (int k = 0; k < KNN_K; ++k) {
    int nb = ip[k];
    float4 g4 = *(const float4*)&Gb[(size_t)nb * CO + o4 * 4];
    m.x = lrelu_max(m.x, g4.x + cv.x);
    m.y = lrelu_max(m.y, g4.y + cv.y);
    m.z = lrelu_max(m.z, g4.z + cv.z);
    m.w = lrelu_max(m.w, g4.w + cv.w);
  }
  ushort4 hi, lo;
  hi.x = f2bf(m.x); lo.x = f2bf(m.x - bf2f(hi.x));
  hi.y = f2bf(m.y); lo.y = f2bf(m.y - bf2f(hi.y));
  hi.z = f2bf(m.z); lo.z = f2bf(m.z - bf2f(hi.z));
  hi.w = f2bf(m.w); lo.w = f2bf(m.w - bf2f(hi.w));
  *(ushort4*)&outHi[bn * CO + o4 * 4] = hi;
  *(ushort4*)&outLo[bn * CO + o4 * 4] = lo;
}

// ---------------- last layer: gather + max over k, partial max over n ------
// Same XCD-locality mapping: 512 blocks = 4 groups x (8 batches x 16 chunks).
template <int CO>
__global__ __launch_bounds__(256) void gather_last_kernel(
    const float* __restrict__ G, const float* __restrict__ C,
    const int* __restrict__ idx, float* __restrict__ part) {
  constexpr int O4 = CO / 4;
  constexpr int PL = 256 / O4;
  constexpr int ITER = 128 / PL;
  const int i = (int)blockIdx.x;
  const int g = i / 128;
  const int j = i % 128;
  const int b = g * 8 + (j & 7);
  const int chunk = j >> 3;  // 0..15
  int tid = (int)threadIdx.x;
  int o4 = tid % O4;
  int pl = tid / O4;
  const float* Gb = G + (size_t)b * N * CO;
  float4 m = make_float4(-1e30f, -1e30f, -1e30f, -1e30f);
  for (int it = 0; it < ITER; ++it) {
    int n = chunk * 128 + it * PL + pl;
    size_t bn = (size_t)b * N + n;
    const int* ip = &idx[bn * KNN_K];
    float4 cv = *(const float4*)&C[bn * CO + o4 * 4];
#pragma unroll
    for (int k = 0; k < KNN_K; ++k) {
      int nb = ip[k];
      float4 g4 = *(const float4*)&Gb[(size_t)nb * CO + o4 * 4];
      m.x = lrelu_max(m.x, g4.x + cv.x);
      m.y = lrelu_max(m.y, g4.y + cv.y);
      m.z = lrelu_max(m.z, g4.z + cv.z);
      m.w = lrelu_max(m.w, g4.w + cv.w);
    }
  }
  __shared__ __align__(16) float4 red[256];
  red[tid] = m;
  __syncthreads();
  for (int s = 128; s >= O4; s >>= 1) {
    if (tid < s) {
      float4 a = red[tid], bb = red[tid + s];
      red[tid] = make_float4(fmaxf(a.x, bb.x), fmaxf(a.y, bb.y),
                             fmaxf(a.z, bb.z), fmaxf(a.w, bb.w));
    }
    __syncthreads();
  }
  if (tid < O4) {
    *(float4*)&part[((size_t)(b * 16 + chunk)) * CO + tid * 4] = red[tid];
  }
}

// --------- fused final reduce over both 128-channel halves (grid.y=2) ------
template <int CO>
__global__ __launch_bounds__(256) void reduce2_kernel(const float* __restrict__ part,
                                                      float* __restrict__ out) {
  constexpr int O4 = CO / 4;
  int half = blockIdx.y;
  const float* p = part + (size_t)half * B * 16 * CO;
  int gid = blockIdx.x * 256 + (int)threadIdx.x;  // 0 .. B*O4-1
  int b = gid / O4;
  int o4 = gid % O4;
  float4 m = make_float4(-1e30f, -1e30f, -1e30f, -1e30f);
  for (int ch = 0; ch < 16; ++ch) {
    float4 v = *(const float4*)&p[((size_t)(b * 16 + ch)) * CO + o4 * 4];
    m.x = fmaxf(m.x, v.x); m.y = fmaxf(m.y, v.y);
    m.z = fmaxf(m.z, v.z); m.w = fmaxf(m.w, v.w);
  }
  *(float4*)&out[(size_t)b * 256 + half * 128 + o4 * 4] = m;
}

extern "C" void kernel_launch(void* const* d_in, const int* in_sizes, int n_in,
                              void* d_out, int out_size, void* d_ws, size_t ws_size,
                              hipStream_t stream) {
  const float* xyz = (const float*)d_in[0];
  const float* W0 = (const float*)d_in[1];
  const float* s0 = (const float*)d_in[2];
  const float* b0 = (const float*)d_in[3];
  const float* W1 = (const float*)d_in[4];
  const float* s1 = (const float*)d_in[5];
  const float* b1 = (const float*)d_in[6];
  const float* W2 = (const float*)d_in[7];
  const float* s2 = (const float*)d_in[8];
  const float* b2 = (const float*)d_in[9];
  float* out = (float*)d_out;

  const size_t MB = 1024 * 1024;
  char* ws = (char*)d_ws;
  int* idx = (int*)ws;                                        // 2 MB
  unsigned short* FHi = (unsigned short*)(ws + 2 * MB);       // 16 MB (M x <=128 bf16)
  unsigned short* FLo = (unsigned short*)(ws + 18 * MB);      // 16 MB
  float* G = (float*)(ws + 34 * MB);                          // 32 MB
  float* Cb = (float*)(ws + 66 * MB);                         // 32 MB
  unsigned short* wbuf = (unsigned short*)(ws + 98 * MB);     // 256 KB
  float* part = (float*)(ws + 98 * MB + 256 * 1024);          // 512 KB (2 halves)

  knn_kernel<<<B * 32, 256, 0, stream>>>(xyz, idx);

  // Layer 1: ci=3 (pad 4), co=64 — f32 path, output split to bf16 hi/lo
  transform_kernel<4, 64><<<dim3(M / 64, 1), 256, 0, stream>>>(xyz, W0, s0, b0, G, Cb);
  gatherbf_kernel<64><<<M * 16 / 256, 256, 0, stream>>>(G, Cb, idx, FHi, FLo);

  // Layer 2: K=64, CO=128 — MFMA 3-pass bf16 split
  wprep_kernel<64, 128><<<(64 * 128 + 255) / 256, 256, 0, stream>>>(W1, s1, wbuf);
  mfma_transform_kernel<64, 128><<<dim3(M / 128, 2), 256, 0, stream>>>(
      FHi, FLo, wbuf, b1, G, Cb, (size_t)64 * 128);
  gatherbf_kernel<128><<<M * 32 / 256, 256, 0, stream>>>(G, Cb, idx, FHi, FLo);

  // Layer 3: K=128, CO=256 in two 128-channel halves — MFMA
  wprep_kernel<128, 256><<<(128 * 256 + 255) / 256, 256, 0, stream>>>(W2, s2, wbuf);
  for (int h = 0; h < 2; ++h) {
    mfma_transform_kernel<128, 128><<<dim3(M / 128, 2), 256, 0, stream>>>(
        FHi, FLo, wbuf + (size_t)h * 128 * 128, b2 + h * 128, G, Cb,
        (size_t)128 * 256);
    gather_last_kernel<128><<<B * 16, 256, 0, stream>>>(
        G, Cb, idx, part + (size_t)h * B * 16 * 128);
  }
  reduce2_kernel<128><<<dim3(B * 128 / 4 / 256, 2), 256, 0, stream>>>(part, out);
}

// Round 14
// 270.008 us; speedup vs baseline: 1.3861x; 1.0579x over previous
//
#include <hip/hip_runtime.h>

#define KNN_K 8
constexpr int B = 32;
constexpr int N = 2048;
constexpr int M = B * N;  // 65536 points

typedef __attribute__((ext_vector_type(8))) short short8v;  // 8 bf16
typedef __attribute__((ext_vector_type(4))) float f32x4;

__device__ __forceinline__ float lrelu_max(float m, float y) {
  return fmaxf(m, fmaxf(y, 0.2f * y));
}
__device__ __forceinline__ unsigned short f2bf(float x) {  // RNE f32->bf16
  unsigned int u = __float_as_uint(x);
  unsigned int r = u + 0x7FFFu + ((u >> 16) & 1u);
  return (unsigned short)(r >> 16);
}
__device__ __forceinline__ float bf2f(unsigned short h) {
  return __uint_as_float(((unsigned int)h) << 16);
}

// ---------------- KNN on reshape(xyz,(B,3,N)) pseudo-points ----------------
// 4 threads/query, interleaved quarters. Deferred selection in registers,
// 4-deep shift-in queue. Key encode exploits pd <= 0: mono = ~bits(pd).

#define CAS_T(i, j)                                        \
  {                                                        \
    unsigned long long _x = t[i], _y = t[j];               \
    bool _p = _x < _y;                                     \
    t[i] = _p ? _y : _x;                                   \
    t[j] = _p ? _x : _y;                                   \
  }
#define CAS_TOP(i, j)                                      \
  {                                                        \
    unsigned long long _x = top[i], _y = top[j];           \
    bool _p = _x < _y;                                     \
    top[i] = _p ? _y : _x;                                 \
    top[j] = _p ? _x : _y;                                 \
  }

__global__ __launch_bounds__(256) void knn_kernel(const float* __restrict__ xyz,
                                                  int* __restrict__ idx) {
  __shared__ __align__(16) float4 spt[N];  // 32 KB; reused as merge scratch
  int b = blockIdx.x >> 5;     // 32 blocks per batch
  int nblk = blockIdx.x & 31;  // 64 queries per block
  const float* F = xyz + (size_t)b * N * 3;
  for (int i = threadIdx.x; i < N; i += 256) {
    float x = F[i], y = F[N + i], z = F[2 * N + i];
    spt[i] = make_float4(x, y, z, (x * x + y * y) + z * z);
  }
  __syncthreads();
  const int tid = (int)threadIdx.x;
  const int ln = tid >> 2;  // 0..63 local query
  const int q = tid & 3;    // quarter
  const int n = nblk * 64 + ln;
  float4 pn = spt[n];
  const float npnw = -pn.w;

  unsigned long long top[8];   // sorted desc u64 keys; 0 = empty
  unsigned long long bufr[4];  // 4-deep shift-in queue; entries >= cnt stale
#pragma unroll
  for (int k = 0; k < 8; ++k) top[k] = 0ull;
#pragma unroll
  for (int k = 0; k < 4; ++k) bufr[k] = 0ull;
  float thr = -1e30f;
  int cnt = 0;

  auto flush = [&]() {
    unsigned long long t[4];
#pragma unroll
    for (int i = 0; i < 4; ++i) t[i] = (i < cnt) ? bufr[i] : 0ull;
    // sort 4 desc (5 CAS)
    CAS_T(0, 1) CAS_T(2, 3) CAS_T(0, 2) CAS_T(1, 3) CAS_T(1, 2)
    // bitonic half-clean vs zero-padded reversed t: only tail touched
    {
      unsigned long long x;
      x = top[4]; top[4] = x > t[3] ? x : t[3];
      x = top[5]; top[5] = x > t[2] ? x : t[2];
      x = top[6]; top[6] = x > t[1] ? x : t[1];
      x = top[7]; top[7] = x > t[0] ? x : t[0];
    }
    // bitonic clean 8 desc (12 CAS)
    CAS_TOP(0, 4) CAS_TOP(1, 5) CAS_TOP(2, 6) CAS_TOP(3, 7)
    CAS_TOP(0, 2) CAS_TOP(1, 3) CAS_TOP(4, 6) CAS_TOP(5, 7)
    CAS_TOP(0, 1) CAS_TOP(2, 3) CAS_TOP(4, 5) CAS_TOP(6, 7)
    cnt = 0;
    if (top[7] != 0ull) {  // guard: while not full, keep thr=-1e30 (accept all)
      thr = __uint_as_float(~(unsigned int)(top[7] >> 32));
    }
  };

  unsigned int mnot = ~(unsigned int)q;  // ~m, maintained by induction (-4/iter)
#pragma unroll 4
  for (int j = 0; j < N / 4; ++j) {
    int m = (j << 2) | q;
    float4 pm = spt[m];
    float dot = (pn.x * pm.x + pn.y * pm.y) + pn.z * pm.z;
    float pd = __builtin_fmaf(2.0f, dot, npnw) - pm.w;  // == -pn.w -(-2dot) -pm.w
    if (pd > thr) {  // strict: ties keep the earlier (lower) index, as top_k
      unsigned long long key =
          ((unsigned long long)(~__float_as_uint(pd)) << 32) |
          (unsigned long long)mnot;
      bufr[3] = bufr[2]; bufr[2] = bufr[1]; bufr[1] = bufr[0];
      bufr[0] = key;
      ++cnt;
    }
    mnot -= 4u;
    if (__any(cnt >= 4)) flush();
  }
  flush();  // drain partial queues

  __syncthreads();  // all scans done; safe to overwrite spt
  unsigned long long* km = (unsigned long long*)spt;  // [256][8] = 16 KB
#pragma unroll
  for (int k = 0; k < 8; ++k) km[tid * 8 + k] = top[k];
  __syncthreads();
  if (q == 0) {
    int h[4] = {0, 0, 0, 0};
    int* op = idx + ((size_t)b * N + n) * KNN_K;
#pragma unroll
    for (int k = 0; k < KNN_K; ++k) {
      unsigned long long bk = 0ull;
      int bq = 0;
#pragma unroll
      for (int qq = 0; qq < 4; ++qq) {
        unsigned long long kk = km[(((ln << 2) | qq)) * 8 + h[qq]];
        if (kk > bk) { bk = kk; bq = qq; }
      }
      op[k] = (int)(0xFFFFFFFFu - (unsigned int)(bk & 0xFFFFFFFFull));
      h[bq]++;
    }
  }
}

// ---------------- layer-1 transform (tiny K): f32 VALU path ----------------
template <int CI, int CO>
__global__ __launch_bounds__(256) void transform_kernel(
    const float* __restrict__ f, const float* __restrict__ W,
    const float* __restrict__ s, const float* __restrict__ bsh,
    float* __restrict__ G, float* __restrict__ C) {
  constexpr int KC = CI;  // CI == 4 only
  __shared__ __align__(16) float fs[KC][68];
  __shared__ __align__(16) float was[KC][68];
  __shared__ __align__(16) float wds[KC][68];
  const int base = blockIdx.x * 64;
  const int o0 = blockIdx.y * 64;
  const int tid = threadIdx.x;
  const int tx = tid & 15, ty = tid >> 4;
  float accG[4][4] = {{0}};
  float accC[4][4] = {{0}};
  for (int i = tid; i < 64 * 4; i += 256) {
    int c = i & 3, p = i >> 2;
    fs[c][p] = (c < 3) ? f[(size_t)(base + p) * 3 + c] : 0.0f;
  }
  if (tid < 64) {
    int o = tid;
    float sc = s[o0 + o];
    const float* wr = &W[(size_t)(o0 + o) * 6];
#pragma unroll
    for (int c = 0; c < 4; ++c) {
      float wa = (c < 3) ? wr[c] : 0.0f;
      float wb = (c < 3) ? wr[3 + c] : 0.0f;
      was[c][o] = sc * wa;
      wds[c][o] = sc * (wb - wa);
    }
  }
  __syncthreads();
#pragma unroll
  for (int c = 0; c < KC; ++c) {
    float4 av = *(const float4*)&fs[c][ty * 4];
    float4 wg = *(const float4*)&was[c][tx * 4];
    float4 wd = *(const float4*)&wds[c][tx * 4];
    float a[4] = {av.x, av.y, av.z, av.w};
    float g[4] = {wg.x, wg.y, wg.z, wg.w};
    float d[4] = {wd.x, wd.y, wd.z, wd.w};
#pragma unroll
    for (int i = 0; i < 4; ++i)
#pragma unroll
      for (int j = 0; j < 4; ++j) {
        accG[i][j] = fmaf(a[i], g[j], accG[i][j]);
        accC[i][j] = fmaf(a[i], d[j], accC[i][j]);
      }
  }
  float4 sh = *(const float4*)&bsh[o0 + tx * 4];
  float shv[4] = {sh.x, sh.y, sh.z, sh.w};
#pragma unroll
  for (int i = 0; i < 4; ++i) {
    size_t row = (size_t)(base + ty * 4 + i);
    float4 g4 = make_float4(accG[i][0], accG[i][1], accG[i][2], accG[i][3]);
    float4 c4 = make_float4(accC[i][0] + shv[0], accC[i][1] + shv[1],
                            accC[i][2] + shv[2], accC[i][3] + shv[3]);
    *(float4*)&G[row * CO + o0 + tx * 4] = g4;
    *(float4*)&C[row * CO + o0 + tx * 4] = c4;
  }
}

// ------------- weight prep: split s*Wa, s*(Wb-Wa) into bf16 hi/lo ----------
template <int CI, int CO>
__global__ __launch_bounds__(256) void wprep_kernel(
    const float* __restrict__ W, const float* __restrict__ s,
    unsigned short* __restrict__ wb) {
  int i = blockIdx.x * 256 + (int)threadIdx.x;  // o*CI + k
  if (i >= CI * CO) return;
  int o = i / CI, k = i % CI;
  float sc = s[o];
  float w0 = W[(size_t)o * 2 * CI + k];
  float wa = sc * w0;
  float wd = sc * (W[(size_t)o * 2 * CI + CI + k] - w0);
  unsigned short waH = f2bf(wa);
  unsigned short waL = f2bf(wa - bf2f(waH));
  unsigned short wdH = f2bf(wd);
  unsigned short wdL = f2bf(wd - bf2f(wdH));
  wb[i] = waH;
  wb[CI * CO + i] = waL;
  wb[2 * CI * CO + i] = wdH;
  wb[3 * CI * CO + i] = wdL;
}

// --------- MFMA transform (2-pass): G = A·(Wh+Wl), C = A·(Wdh+Wdl) --------
// A is bf16-only features; W kept hi+lo (exact). 4 MFMAs per fragment pair.
// grid.z selects an output-channel half (layer 3); z=0-only for layer 2.
template <int K, int CO>
__global__ __launch_bounds__(256) void mfma_transform_kernel(
    const unsigned short* __restrict__ A, const unsigned short* __restrict__ wb,
    const float* __restrict__ bsh, float* __restrict__ G0,
    float* __restrict__ C0, float* __restrict__ G1, float* __restrict__ C1,
    size_t arrStride, size_t wbHalfOff, int bshHalfOff) {
  constexpr int KP = 40;  // padded LDS k-stride -> 80B rows, no 8-way conflict
  __shared__ unsigned short Ah[128][KP];
  __shared__ unsigned short Bw[4][64][KP];
  const int z = (int)blockIdx.z;
  const unsigned short* wbp = wb + (size_t)z * wbHalfOff;
  const float* bshp = bsh + z * bshHalfOff;
  float* G = z ? G1 : G0;
  float* C = z ? C1 : C0;
  const int base = blockIdx.x * 128;
  const int o0 = blockIdx.y * 64;
  const int tid = (int)threadIdx.x;
  const int lane = tid & 63;
  const int wid = tid >> 6;
  const int wr = wid >> 1;  // wave row-half (64 pts)
  const int wc = wid & 1;   // wave col-half (32 outs)
  const int l15 = lane & 15;
  const int lk = (lane >> 4) * 8;  // fragment k-base

  f32x4 zero = {0.f, 0.f, 0.f, 0.f};
  f32x4 accG[4][2], accC[4][2];
#pragma unroll
  for (int i = 0; i < 4; ++i)
#pragma unroll
    for (int j = 0; j < 2; ++j) { accG[i][j] = zero; accC[i][j] = zero; }

  const int arow = tid >> 1;        // 0..127
  const int akh = (tid & 1) * 16;   // 0 / 16
  const int bo = tid & 63;          // weight out-row
  const int barr = tid >> 6;        // which of 4 arrays

  for (int kc0 = 0; kc0 < K; kc0 += 32) {
    {  // stage A: 128 x 32 bf16
      const unsigned short* pa = &A[(size_t)(base + arow) * K + kc0 + akh];
      short8v h0 = *(const short8v*)pa;
      short8v h1 = *(const short8v*)(pa + 8);
      *(short8v*)&Ah[arow][akh] = h0;
      *(short8v*)&Ah[arow][akh + 8] = h1;
      // stage B: 4 arrays x 64 outs x 32 k
      const unsigned short* pb =
          &wbp[(size_t)barr * arrStride + (size_t)(o0 + bo) * K + kc0];
#pragma unroll
      for (int j = 0; j < 4; ++j) {
        short8v v = *(const short8v*)(pb + j * 8);
        *(short8v*)&Bw[barr][bo][j * 8] = v;
      }
    }
    __syncthreads();
    short8v ah[4], bah[2], bal[2], bdh[2], bdl[2];
#pragma unroll
    for (int mf = 0; mf < 4; ++mf)
      ah[mf] = *(const short8v*)&Ah[wr * 64 + mf * 16 + l15][lk];
#pragma unroll
    for (int nf = 0; nf < 2; ++nf) {
      int oo = wc * 32 + nf * 16 + l15;
      bah[nf] = *(const short8v*)&Bw[0][oo][lk];
      bal[nf] = *(const short8v*)&Bw[1][oo][lk];
      bdh[nf] = *(const short8v*)&Bw[2][oo][lk];
      bdl[nf] = *(const short8v*)&Bw[3][oo][lk];
    }
#pragma unroll
    for (int mf = 0; mf < 4; ++mf)
#pragma unroll
      for (int nf = 0; nf < 2; ++nf) {
        accG[mf][nf] = __builtin_amdgcn_mfma_f32_16x16x32_bf16(
            ah[mf], bah[nf], accG[mf][nf], 0, 0, 0);
        accG[mf][nf] = __builtin_amdgcn_mfma_f32_16x16x32_bf16(
            ah[mf], bal[nf], accG[mf][nf], 0, 0, 0);
        accC[mf][nf] = __builtin_amdgcn_mfma_f32_16x16x32_bf16(
            ah[mf], bdh[nf], accC[mf][nf], 0, 0, 0);
        accC[mf][nf] = __builtin_amdgcn_mfma_f32_16x16x32_bf16(
            ah[mf], bdl[nf], accC[mf][nf], 0, 0, 0);
      }
    __syncthreads();
  }
  float sh[2];
  sh[0] = bshp[o0 + wc * 32 + l15];
  sh[1] = bshp[o0 + wc * 32 + 16 + l15];
#pragma unroll
  for (int mf = 0; mf < 4; ++mf)
#pragma unroll
    for (int nf = 0; nf < 2; ++nf) {
      int col = o0 + wc * 32 + nf * 16 + l15;
#pragma unroll
      for (int r = 0; r < 4; ++r) {
        int row = base + wr * 64 + mf * 16 + (lane >> 4) * 4 + r;
        G[(size_t)row * CO + col] = accG[mf][nf][r];
        C[(size_t)row * CO + col] = accC[mf][nf][r] + sh[nf];
      }
    }
}

// ------- gather + leaky + max over k; emits bf16 features (hi only) --------
// XCD-locality: batch = g*8 + (blockIdx%8) so a batch stays on one XCD L2.
template <int CO>
__global__ __launch_bounds__(256) void gatherbf_kernel(
    const float* __restrict__ G, const float* __restrict__ C,
    const int* __restrict__ idx, unsigned short* __restrict__ outHi) {
  constexpr int O4 = CO / 4;
  constexpr int PPB = 256 / O4;        // points per block
  constexpr int BPB = N / PPB;         // blocks per batch
  constexpr int GRP = 8 * BPB;         // blocks per batch-group
  const int i = (int)blockIdx.x;
  const int g = i / GRP;
  const int j = i % GRP;
  const int b = g * 8 + (j & 7);
  const int chunk = j >> 3;
  const int tid = (int)threadIdx.x;
  const int o4 = tid % O4;
  const int lp = tid / O4;
  const size_t bn = (size_t)b * N + chunk * PPB + lp;
  const int* ip = &idx[bn * KNN_K];
  const float* Gb = G + (size_t)b * N * CO;
  float4 cv = *(const float4*)&C[bn * CO + o4 * 4];
  float4 m = make_float4(-1e30f, -1e30f, -1e30f, -1e30f);
#pragma unroll
  for (int k = 0; k < KNN_K; ++k) {
    int nb = ip[k];
    float4 g4 = *(const float4*)&Gb[(size_t)nb * CO + o4 * 4];
    m.x = lrelu_max(m.x, g4.x + cv.x);
    m.y = lrelu_max(m.y, g4.y + cv.y);
    m.z = lrelu_max(m.z, g4.z + cv.z);
    m.w = lrelu_max(m.w, g4.w + cv.w);
  }
  ushort4 hi;
  hi.x = f2bf(m.x); hi.y = f2bf(m.y); hi.z = f2bf(m.z); hi.w = f2bf(m.w);
  *(ushort4*)&outHi[bn * CO + o4 * 4] = hi;
}

// ---------------- last layer: gather + max over k, partial max over n ------
// grid.y selects the output-channel half (fused path); same XCD mapping.
template <int CO>
__global__ __launch_bounds__(256) void gather_last_kernel(
    const float* __restrict__ G0, const float* __restrict__ C0,
    const float* __restrict__ G1, const float* __restrict__ C1,
    const int* __restrict__ idx, float* __restrict__ part) {
  constexpr int O4 = CO / 4;
  constexpr int PL = 256 / O4;
  constexpr int ITER = 128 / PL;
  const int h = (int)blockIdx.y;
  const float* G = h ? G1 : G0;
  const float* C = h ? C1 : C0;
  float* pt = part + (size_t)h * B * 16 * CO;
  const int i = (int)blockIdx.x;
  const int g = i / 128;
  const int j = i % 128;
  const int b = g * 8 + (j & 7);
  const int chunk = j >> 3;  // 0..15
  int tid = (int)threadIdx.x;
  int o4 = tid % O4;
  int pl = tid / O4;
  const float* Gb = G + (size_t)b * N * CO;
  float4 m = make_float4(-1e30f, -1e30f, -1e30f, -1e30f);
  for (int it = 0; it < ITER; ++it) {
    int n = chunk * 128 + it * PL + pl;
    size_t bn = (size_t)b * N + n;
    const int* ip = &idx[bn * KNN_K];
    float4 cv = *(const float4*)&C[bn * CO + o4 * 4];
#pragma unroll
    for (int k = 0; k < KNN_K; ++k) {
      int nb = ip[k];
      float4 g4 = *(const float4*)&Gb[(size_t)nb * CO + o4 * 4];
      m.x = lrelu_max(m.x, g4.x + cv.x);
      m.y = lrelu_max(m.y, g4.y + cv.y);
      m.z = lrelu_max(m.z, g4.z + cv.z);
      m.w = lrelu_max(m.w, g4.w + cv.w);
    }
  }
  __shared__ __align__(16) float4 red[256];
  red[tid] = m;
  __syncthreads();
  for (int s = 128; s >= O4; s >>= 1) {
    if (tid < s) {
      float4 a = red[tid], bb = red[tid + s];
      red[tid] = make_float4(fmaxf(a.x, bb.x), fmaxf(a.y, bb.y),
                             fmaxf(a.z, bb.z), fmaxf(a.w, bb.w));
    }
    __syncthreads();
  }
  if (tid < O4) {
    *(float4*)&pt[((size_t)(b * 16 + chunk)) * CO + tid * 4] = red[tid];
  }
}

// --------- fused final reduce over both 128-channel halves (grid.y=2) ------
template <int CO>
__global__ __launch_bounds__(256) void reduce2_kernel(const float* __restrict__ part,
                                                      float* __restrict__ out) {
  constexpr int O4 = CO / 4;
  int half = blockIdx.y;
  const float* p = part + (size_t)half * B * 16 * CO;
  int gid = blockIdx.x * 256 + (int)threadIdx.x;  // 0 .. B*O4-1
  int b = gid / O4;
  int o4 = gid % O4;
  float4 m = make_float4(-1e30f, -1e30f, -1e30f, -1e30f);
  for (int ch = 0; ch < 16; ++ch) {
    float4 v = *(const float4*)&p[((size_t)(b * 16 + ch)) * CO + o4 * 4];
    m.x = fmaxf(m.x, v.x); m.y = fmaxf(m.y, v.y);
    m.z = fmaxf(m.z, v.z); m.w = fmaxf(m.w, v.w);
  }
  *(float4*)&out[(size_t)b * 256 + half * 128 + o4 * 4] = m;
}

extern "C" void kernel_launch(void* const* d_in, const int* in_sizes, int n_in,
                              void* d_out, int out_size, void* d_ws, size_t ws_size,
                              hipStream_t stream) {
  const float* xyz = (const float*)d_in[0];
  const float* W0 = (const float*)d_in[1];
  const float* s0 = (const float*)d_in[2];
  const float* b0 = (const float*)d_in[3];
  const float* W1 = (const float*)d_in[4];
  const float* s1 = (const float*)d_in[5];
  const float* b1 = (const float*)d_in[6];
  const float* W2 = (const float*)d_in[7];
  const float* s2 = (const float*)d_in[8];
  const float* b2 = (const float*)d_in[9];
  float* out = (float*)d_out;

  const size_t MB = 1024 * 1024;
  const bool wide = ws_size >= 148 * MB;  // room for G2/C2 (fused layer-3)
  char* ws = (char*)d_ws;
  int* idx = (int*)ws;                                      // 2 MB
  unsigned short* Fb = (unsigned short*)(ws + 2 * MB);      // 16 MB bf16 feats
  float* G = (float*)(ws + 18 * MB);                        // 32 MB
  float* Cb = (float*)(ws + 50 * MB);                       // 32 MB
  float* G2 = wide ? (float*)(ws + 82 * MB) : G;            // 32 MB (wide)
  float* C2 = wide ? (float*)(ws + 114 * MB) : Cb;          // 32 MB (wide)
  size_t tail = wide ? 146 * MB : 82 * MB;
  unsigned short* wbuf = (unsigned short*)(ws + tail);      // 256 KB
  float* part = (float*)(ws + tail + 256 * 1024);           // 512 KB (2 halves)

  knn_kernel<<<B * 32, 256, 0, stream>>>(xyz, idx);

  // Layer 1: ci=3 (pad 4), co=64 — f32 path, bf16 features out
  transform_kernel<4, 64><<<dim3(M / 64, 1), 256, 0, stream>>>(xyz, W0, s0, b0, G, Cb);
  gatherbf_kernel<64><<<M * 16 / 256, 256, 0, stream>>>(G, Cb, idx, Fb);

  // Layer 2: K=64, CO=128 — MFMA 2-pass (W hi+lo, A bf16)
  wprep_kernel<64, 128><<<(64 * 128 + 255) / 256, 256, 0, stream>>>(W1, s1, wbuf);
  mfma_transform_kernel<64, 128><<<dim3(M / 128, 2, 1), 256, 0, stream>>>(
      Fb, wbuf, b1, G, Cb, G, Cb, (size_t)64 * 128, 0, 0);
  gatherbf_kernel<128><<<M * 32 / 256, 256, 0, stream>>>(G, Cb, idx, Fb);

  // Layer 3: K=128, CO=256 in two 128-channel halves — MFMA 2-pass
  wprep_kernel<128, 256><<<(128 * 256 + 255) / 256, 256, 0, stream>>>(W2, s2, wbuf);
  if (wide) {
    mfma_transform_kernel<128, 128><<<dim3(M / 128, 2, 2), 256, 0, stream>>>(
        Fb, wbuf, b2, G, Cb, G2, C2, (size_t)128 * 256, (size_t)128 * 128, 128);
    gather_last_kernel<128><<<dim3(B * 16, 2), 256, 0, stream>>>(
        G, Cb, G2, C2, idx, part);
  } else {
    for (int h = 0; h < 2; ++h) {
      mfma_transform_kernel<128, 128><<<dim3(M / 128, 2, 1), 256, 0, stream>>>(
          Fb, wbuf + (size_t)h * 128 * 128, b2 + h * 128, G, Cb, G, Cb,
          (size_t)128 * 256, 0, 0);
      gather_last_kernel<128><<<dim3(B * 16, 1), 256, 0, stream>>>(
          G, Cb, G, Cb, idx, part + (size_t)h * B * 16 * 128);
    }
  }
  reduce2_kernel<128><<<dim3(B * 128 / 4 / 256, 2), 256, 0, stream>>>(part, out);
}